// Round 6
// baseline (571.529 us; speedup 1.0000x reference)
//
#include <hip/hip_runtime.h>
#include <hip/hip_bf16.h>
#include <math.h>

#define B_ 2
#define N_ 16384
#define M_ 2048
#define D_ 256
#define NHEAD_ 8
#define DH_ 32
#define FF_ 512
#define C_ 50
#define HID_ 128
#define HHID_ 256
#define L_ 4
#define EPS_ 1e-5f
#define TOK_ (B_*M_)   // 4096
// (1/sqrt(32)) * log2(e): folds softmax scale AND exp->exp2 into Q
#define QSCALE_ 0.25507604155757994f

typedef short short8 __attribute__((ext_vector_type(8)));
typedef float f32x4 __attribute__((ext_vector_type(4)));

__device__ __forceinline__ short f2bf(float f) {
  union { float f; unsigned u; } c; c.f = f;
  unsigned u = c.u;
  unsigned r = (u + 0x7FFFu + ((u >> 16) & 1u)) >> 16;
  return (short)r;
}
__device__ __forceinline__ unsigned pack2bf(float a, float b) {
  return ((unsigned)(unsigned short)f2bf(a)) | (((unsigned)(unsigned short)f2bf(b)) << 16);
}
__device__ __forceinline__ float fast_exp2(float x) {
  float r;
  asm("v_exp_f32 %0, %1" : "=v"(r) : "v"(x));
  return r;
}
__device__ __forceinline__ unsigned cvt_pk_bf16(float lo, float hi) {
  unsigned r;
  asm("v_cvt_pk_bf16_f32 %0, %1, %2" : "=v"(r) : "v"(lo), "v"(hi));
  return r;
}

// ---------------- fused embed + pos MLP ----------------
__global__ __launch_bounds__(128) void embed_kernel(
    const float* __restrict__ xyz,
    const float* __restrict__ ew1, const float* __restrict__ eb1,
    const float* __restrict__ ew2, const float* __restrict__ eb2,
    const float* __restrict__ pw1, const float* __restrict__ pb1,
    const float* __restrict__ pw2, const float* __restrict__ pb2,
    float* __restrict__ x) {
  int t = blockIdx.x;           // 0..4095
  int b = t / M_, m = t % M_;
  const float* p = xyz + ((size_t)b * N_ + (size_t)m * 8) * 3;
  float t0 = p[0], t1 = p[1], t2 = p[2];
  __shared__ float he[HID_], hp[HID_];
  int j = threadIdx.x;          // 128 threads
  {
    float a = fmaf(t0, ew1[j], fmaf(t1, ew1[HID_ + j], fmaf(t2, ew1[2 * HID_ + j], eb1[j])));
    he[j] = fmaxf(a, 0.f);
    float c = fmaf(t0, pw1[j], fmaf(t1, pw1[HID_ + j], fmaf(t2, pw1[2 * HID_ + j], pb1[j])));
    hp[j] = fmaxf(c, 0.f);
  }
  __syncthreads();
  for (int d = j; d < D_; d += HID_) {
    float acc = eb2[d] + pb2[d];
    for (int k = 0; k < HID_; ++k) {
      acc = fmaf(he[k], ew2[k * D_ + d], acc);
      acc = fmaf(hp[k], pw2[k * D_ + d], acc);
    }
    x[(size_t)t * D_ + d] = acc;
  }
}

// ---------------- LayerNorm (4 rows/block, one wave each) ----------------
__global__ __launch_bounds__(256) void ln_kernel(
    const float* __restrict__ x, const float* __restrict__ s,
    const float* __restrict__ bb, float* __restrict__ y) {
  int r = blockIdx.x * 4 + (threadIdx.x >> 6);
  int t = threadIdx.x & 63;
  const float4* xr = (const float4*)(x + (size_t)r * D_);
  float4 v = xr[t];
  float sum = v.x + v.y + v.z + v.w;
  #pragma unroll
  for (int o = 1; o < 64; o <<= 1) sum += __shfl_xor(sum, o, 64);
  float mean = sum * (1.f / D_);
  float dx = v.x - mean, dy = v.y - mean, dz = v.z - mean, dw = v.w - mean;
  float vs = dx * dx + dy * dy + dz * dz + dw * dw;
  #pragma unroll
  for (int o = 1; o < 64; o <<= 1) vs += __shfl_xor(vs, o, 64);
  float inv = 1.0f / sqrtf(vs * (1.f / D_) + EPS_);
  float4 sv = ((const float4*)s)[t];
  float4 bv = ((const float4*)bb)[t];
  float4 out;
  out.x = dx * inv * sv.x + bv.x;
  out.y = dy * inv * sv.y + bv.y;
  out.z = dz * inv * sv.z + bv.z;
  out.w = dw * inv * sv.w + bv.w;
  ((float4*)(y + (size_t)r * D_))[t] = out;
}

// ---------------- fp32 tiled GEMM (kept for head2, N=50) ----------------
template <int ACT, int RES>
__global__ __launch_bounds__(256) void gemm_kernel(
    const float* __restrict__ A, const float* __restrict__ W,
    const float* __restrict__ bias, const float* __restrict__ R,
    float* __restrict__ Cc, int K, int Ncols) {
  __shared__ float As[16][68];
  __shared__ float Ws[16][68];
  int m0 = blockIdx.y * 64;
  int n0 = blockIdx.x * 64;
  int tid = threadIdx.x;  // 256
  int tx = tid & 15, ty = tid >> 4;
  float acc[4][4] = {};
  for (int kk = 0; kk < K; kk += 16) {
    for (int i = tid; i < 64 * 16; i += 256) {
      int mm = i >> 4, kq = i & 15;
      As[kq][mm] = A[(size_t)(m0 + mm) * K + kk + kq];
    }
    for (int i = tid; i < 16 * 64; i += 256) {
      int kq = i >> 6, nn = i & 63;
      int n = n0 + nn;
      Ws[kq][nn] = (n < Ncols) ? W[(size_t)(kk + kq) * Ncols + n] : 0.f;
    }
    __syncthreads();
    #pragma unroll
    for (int kq = 0; kq < 16; ++kq) {
      float a[4], w[4];
      #pragma unroll
      for (int i = 0; i < 4; ++i) a[i] = As[kq][ty * 4 + i];
      #pragma unroll
      for (int jj = 0; jj < 4; ++jj) w[jj] = Ws[kq][tx * 4 + jj];
      #pragma unroll
      for (int i = 0; i < 4; ++i)
        #pragma unroll
        for (int jj = 0; jj < 4; ++jj) acc[i][jj] = fmaf(a[i], w[jj], acc[i][jj]);
    }
    __syncthreads();
  }
  #pragma unroll
  for (int i = 0; i < 4; ++i) {
    int m = m0 + ty * 4 + i;
    #pragma unroll
    for (int jj = 0; jj < 4; ++jj) {
      int n = n0 + tx * 4 + jj;
      if (n >= Ncols) continue;
      float v = acc[i][jj] + bias[n];
      if (ACT == 1) v = fmaxf(v, 0.f);
      else if (ACT == 2) v = 0.5f * v * (1.f + erff(v * 0.70710678118654752f));
      if (RES) v += R[(size_t)m * Ncols + n];
      Cc[(size_t)m * Ncols + n] = v;
    }
  }
}

// ---------------- bf16 MFMA GEMM: BM=32, BN=64, BK=32, 4 waves (16x32 each) ----------------
template <int ACT, int RES>
__device__ __forceinline__ void gemm_body(
    const float* __restrict__ A, const float* __restrict__ W,
    const float* __restrict__ bias, const float* __restrict__ R,
    float* __restrict__ Cc, short* __restrict__ out16, float oscale,
    int K, int Ncols, int m0, int n0) {
  __shared__ short As[32][40];
  __shared__ short Bs[64][40];
  int tid = threadIdx.x;
  int w = tid >> 6, l = tid & 63;
  int lq = l & 15, lg = l >> 4;
  int wr = (w & 1) * 16, wc = (w >> 1) * 32;
  int ar = tid >> 3, ak = (tid & 7) * 4;
  int wn = tid & 63, wk = (tid >> 6) * 8;
  f32x4 acc0 = {0.f, 0.f, 0.f, 0.f};
  f32x4 acc1 = {0.f, 0.f, 0.f, 0.f};
  for (int kk = 0; kk < K; kk += 32) {
    __syncthreads();
    {
      float4 a4 = *(const float4*)(A + (size_t)(m0 + ar) * K + kk + ak);
      uint2 au;
      au.x = pack2bf(a4.x, a4.y);
      au.y = pack2bf(a4.z, a4.w);
      *(uint2*)&As[ar][ak] = au;
      const float* wp = W + (size_t)(kk + wk) * Ncols + n0 + wn;
      float w0 = wp[0];
      float w1 = wp[(size_t)Ncols];
      float w2 = wp[2 * (size_t)Ncols];
      float w3 = wp[3 * (size_t)Ncols];
      float w4 = wp[4 * (size_t)Ncols];
      float w5 = wp[5 * (size_t)Ncols];
      float w6 = wp[6 * (size_t)Ncols];
      float w7 = wp[7 * (size_t)Ncols];
      uint4 wu;
      wu.x = pack2bf(w0, w1); wu.y = pack2bf(w2, w3);
      wu.z = pack2bf(w4, w5); wu.w = pack2bf(w6, w7);
      *(uint4*)&Bs[wn][wk] = wu;
    }
    __syncthreads();
    short8 af = *(short8*)&As[wr + lq][lg * 8];
    short8 b0 = *(short8*)&Bs[wc + lq][lg * 8];
    short8 b1 = *(short8*)&Bs[wc + 16 + lq][lg * 8];
    acc0 = __builtin_amdgcn_mfma_f32_16x16x32_bf16(af, b0, acc0, 0, 0, 0);
    acc1 = __builtin_amdgcn_mfma_f32_16x16x32_bf16(af, b1, acc1, 0, 0, 0);
  }
  int row = m0 + wr + lg * 4;
  #pragma unroll
  for (int r = 0; r < 4; ++r) {
    #pragma unroll
    for (int fj = 0; fj < 2; ++fj) {
      int col = n0 + wc + fj * 16 + lq;
      float v = (fj ? acc1[r] : acc0[r]) + bias[col];
      if (ACT == 1) v = fmaxf(v, 0.f);
      else if (ACT == 2) v = 0.5f * v * (1.f + erff(v * 0.70710678118654752f));
      if (RES) v += R[(size_t)(row + r) * Ncols + col];
      if (out16) out16[(size_t)(row + r) * Ncols + col] = f2bf(v * oscale);
      else Cc[(size_t)(row + r) * Ncols + col] = v;
    }
  }
}

template <int ACT, int RES>
__global__ __launch_bounds__(256) void gemm_mfma(
    const float* __restrict__ A, const float* __restrict__ W,
    const float* __restrict__ bias, const float* __restrict__ R,
    float* __restrict__ Cc, int K, int Ncols) {
  gemm_body<ACT, RES>(A, W, bias, R, Cc, nullptr, 1.f, K, Ncols, blockIdx.y * 32, blockIdx.x * 64);
}

// Q -> bf16 (scaled by QSCALE_), K -> bf16, V -> fp32
__global__ __launch_bounds__(256) void qkv_mfma(
    const float* __restrict__ A,
    const float* __restrict__ Wq, const float* __restrict__ Wk, const float* __restrict__ Wv,
    const float* __restrict__ bq, const float* __restrict__ bk, const float* __restrict__ bv,
    short* __restrict__ q16, short* __restrict__ k16, float* __restrict__ vb) {
  int sel = blockIdx.x >> 2;
  int n0 = (blockIdx.x & 3) << 6;
  const float* W = sel == 0 ? Wq : (sel == 1 ? Wk : Wv);
  const float* bb = sel == 0 ? bq : (sel == 1 ? bk : bv);
  short* out16 = sel == 0 ? q16 : (sel == 1 ? k16 : nullptr);
  float oscale = sel == 0 ? QSCALE_ : 1.f;
  gemm_body<0, 0>(A, W, bb, nullptr, vb, out16, oscale, D_, D_, blockIdx.y * 32, n0);
}

// ---------------- V transpose: vb fp32 [tok][256] -> vt16 bf16 [b][h][32][2048] ----------------
__global__ __launch_bounds__(256) void vtrans_kernel(
    const float* __restrict__ vb, short* __restrict__ vt16) {
  int bid = blockIdx.x;
  int mt = bid & 31;
  int h = (bid >> 5) & 7;
  int b = bid >> 8;
  __shared__ short ts[64][34];
  int m0 = mt * 64;
  int tid = threadIdx.x;
  int mm = tid >> 2, dd = (tid & 3) * 8;
  const float* vp = vb + (size_t)(b * M_ + m0 + mm) * D_ + h * DH_ + dd;
  float4 a0 = ((const float4*)vp)[0];
  float4 a1 = ((const float4*)vp)[1];
  ts[mm][dd + 0] = f2bf(a0.x); ts[mm][dd + 1] = f2bf(a0.y);
  ts[mm][dd + 2] = f2bf(a0.z); ts[mm][dd + 3] = f2bf(a0.w);
  ts[mm][dd + 4] = f2bf(a1.x); ts[mm][dd + 5] = f2bf(a1.y);
  ts[mm][dd + 6] = f2bf(a1.z); ts[mm][dd + 7] = f2bf(a1.w);
  __syncthreads();
  int d = tid >> 3, mc = (tid & 7) * 8;
  short8 r;
  #pragma unroll
  for (int j = 0; j < 8; ++j) r[j] = ts[mc + j][d];
  *(short8*)&vt16[(size_t)((b * NHEAD_ + h) * DH_ + d) * M_ + m0 + mc] = r;
}

// ---------------- flash attention: barrier-free, KVBLK=128, direct global K/V ----------------
#define PSTR 136   // per-wave P row stride (shorts)
__global__ __launch_bounds__(256) void attn_mfma_kernel(
    const short* __restrict__ q16, const short* __restrict__ k16,
    const short* __restrict__ vt16, float* __restrict__ o) {
  __shared__ short Ps[4][16][PSTR];   // 17408 B, per-wave
  int bid = blockIdx.x;
  int qt = bid & 31;
  int h  = (bid >> 5) & 7;
  int b  = bid >> 8;
  int tid = threadIdx.x;
  int w  = tid >> 6;
  int l  = tid & 63;
  int lq = l & 15;
  int lg = l >> 4;

  // Q frag: bf16, pre-scaled (log2-domain)
  short8 qf = *(const short8*)&q16[(size_t)(b * M_ + qt * 64 + w * 16 + lq) * D_ + h * DH_ + lg * 8];

  // K fragment base: row (t*16+lq), k-dim lg*8; direct global (L2-resident)
  const short* kbase = k16 + ((size_t)(b * M_) + lq) * D_ + h * DH_ + lg * 8;
  // V^T fragment base: rows lq / lq+16, kv-dim lg*8
  const short* vbase = vt16 + (size_t)((b * NHEAD_ + h) * DH_ + lq) * M_ + lg * 8;

  float m_i = -INFINITY, l_i = 0.f;
  f32x4 o0 = {0.f, 0.f, 0.f, 0.f};   // O^T: d = lg*4+r,      q-col = lq
  f32x4 o1 = {0.f, 0.f, 0.f, 0.f};   // O^T: d = 16 + lg*4+r, q-col = lq

  for (int kt = 0; kt < M_ / 128; ++kt) {
    // S'^T[kv][q] over 128 kv (log2-domain)
    f32x4 st[8];
    #pragma unroll
    for (int t = 0; t < 8; ++t) {
      short8 kf = *(const short8*)(kbase + (size_t)(kt * 128 + t * 16) * D_);
      f32x4 z = {0.f, 0.f, 0.f, 0.f};
      st[t] = __builtin_amdgcn_mfma_f32_16x16x32_bf16(kf, qf, z, 0, 0, 0);
    }
    float smax = -INFINITY;
    #pragma unroll
    for (int t = 0; t < 8; ++t)
      #pragma unroll
      for (int r2 = 0; r2 < 4; ++r2) smax = fmaxf(smax, st[t][r2]);
    smax = fmaxf(smax, __shfl_xor(smax, 16, 64));
    smax = fmaxf(smax, __shfl_xor(smax, 32, 64));
    float m_new = fmaxf(m_i, smax);
    float fac = fast_exp2(m_i - m_new);
    float lsum = 0.f;
    #pragma unroll
    for (int t = 0; t < 8; ++t)
      #pragma unroll
      for (int r2 = 0; r2 < 4; ++r2) {
        st[t][r2] = fast_exp2(st[t][r2] - m_new);
        lsum += st[t][r2];
      }
    lsum += __shfl_xor(lsum, 16, 64);
    lsum += __shfl_xor(lsum, 32, 64);
    l_i = l_i * fac + lsum;
    m_i = m_new;
    #pragma unroll
    for (int r2 = 0; r2 < 4; ++r2) { o0[r2] *= fac; o1[r2] *= fac; }
    // pack P (bf16) into per-wave LDS: Ps[w][q][kv] (wave-synchronous, no barrier)
    {
      unsigned* pw = (unsigned*)&Ps[w][lq][0];
      #pragma unroll
      for (int t = 0; t < 8; ++t) {
        uint2 pk;
        pk.x = cvt_pk_bf16(st[t][0], st[t][1]);
        pk.y = cvt_pk_bf16(st[t][2], st[t][3]);
        *(uint2*)(pw + t * 8 + lg * 2) = pk;
      }
    }
    // O^T += V^T · P  (4 kv-chunks x 2 d-halves), V direct from global
    #pragma unroll
    for (int c = 0; c < 4; ++c) {
      short8 pf = *(short8*)&Ps[w][lq][c * 32 + lg * 8];
      short8 v0 = *(const short8*)(vbase + kt * 128 + c * 32);
      short8 v1 = *(const short8*)(vbase + 16 * M_ + kt * 128 + c * 32);
      o0 = __builtin_amdgcn_mfma_f32_16x16x32_bf16(v0, pf, o0, 0, 0, 0);
      o1 = __builtin_amdgcn_mfma_f32_16x16x32_bf16(v1, pf, o1, 0, 0, 0);
    }
  }
  float invl = 1.f / l_i;
  float* op = o + (size_t)(b * M_ + qt * 64 + w * 16 + lq) * D_ + h * DH_;
  #pragma unroll
  for (int r2 = 0; r2 < 4; ++r2) {
    op[lg * 4 + r2]      = o0[r2] * invl;
    op[16 + lg * 4 + r2] = o1[r2] * invl;
  }
}

// ---------------- KNN top-3 + gather/mean ----------------
__global__ __launch_bounds__(512) void knn_kernel(
    const float* __restrict__ xyz, const float* __restrict__ lt,
    float* __restrict__ out) {
  __shared__ float4 tok[2056];   // 2048 + 8 pad
  int b = blockIdx.x >> 8;                  // 256 blocks per batch
  int q0 = (blockIdx.x & 255) << 6;         // 64 queries per block
  int tid = threadIdx.x;
  for (int i = tid; i < M_; i += 512) {
    const float* tp = xyz + ((size_t)b * N_ + (size_t)i * 8) * 3;
    float a = tp[0], bb = tp[1], cc = tp[2];
    tok[i + (i >> 8)] = make_float4(a, bb, cc, a * a + bb * bb + cc * cc);
  }
  __syncthreads();
  int qi = tid >> 3, sl = tid & 7;
  int n = q0 + qi;
  const float* qp = xyz + ((size_t)b * N_ + n) * 3;
  float qx = qp[0], qy = qp[1], qz = qp[2];
  float q2 = qx * qx + qy * qy + qz * qz;
  float dd0 = INFINITY, dd1 = INFINITY, dd2 = INFINITY;
  int ii0 = 0, ii1 = 0, ii2 = 0;
  const float4* cp = &tok[sl * 257];
  int mb = sl << 8;
  #pragma unroll 4
  for (int j = 0; j < 256; ++j) {
    float4 t = cp[j];
    float dot = fmaf(qx, t.x, fmaf(qy, t.y, qz * t.z));
    float d = fmaxf(q2 + t.w - 2.f * dot, 0.f);
    if (d < dd2) {
      int m = mb + j;
      if (d < dd1) {
        dd2 = dd1; ii2 = ii1;
        if (d < dd0) { dd1 = dd0; ii1 = ii0; dd0 = d; ii0 = m; }
        else         { dd1 = d;  ii1 = m; }
      } else         { dd2 = d;  ii2 = m; }
    }
  }
  auto insT = [&](float d, int i) {
    if (d < dd2 || (d == dd2 && i < ii2)) {
      if (d < dd1 || (d == dd1 && i < ii1)) {
        dd2 = dd1; ii2 = ii1;
        if (d < dd0 || (d == dd0 && i < ii0)) { dd1 = dd0; ii1 = ii0; dd0 = d; ii0 = i; }
        else { dd1 = d; ii1 = i; }
      } else { dd2 = d; ii2 = i; }
    }
  };
  #pragma unroll
  for (int off = 1; off < 8; off <<= 1) {
    float pd0 = __shfl_xor(dd0, off, 64); int pi0 = __shfl_xor(ii0, off, 64);
    float pd1 = __shfl_xor(dd1, off, 64); int pi1 = __shfl_xor(ii1, off, 64);
    float pd2 = __shfl_xor(dd2, off, 64); int pi2 = __shfl_xor(ii2, off, 64);
    insT(pd0, pi0); insT(pd1, pi1); insT(pd2, pi2);
  }
  const float* l0 = lt + ((size_t)b * M_ + ii0) * C_;
  const float* l1 = lt + ((size_t)b * M_ + ii1) * C_;
  const float* l2 = lt + ((size_t)b * M_ + ii2) * C_;
  float* op = out + ((size_t)b * N_ + n) * C_;
  for (int cc = sl; cc < C_; cc += 8)
    op[cc] = (l0[cc] + l1[cc] + l2[cc]) * (1.f / 3.f);
}

extern "C" void kernel_launch(void* const* d_in, const int* in_sizes, int n_in,
                              void* d_out, int out_size, void* d_ws, size_t ws_size,
                              hipStream_t stream) {
  const float* xyz  = (const float*)d_in[0];
  const float* ew1  = (const float*)d_in[1];
  const float* eb1  = (const float*)d_in[2];
  const float* ew2  = (const float*)d_in[3];
  const float* eb2  = (const float*)d_in[4];
  const float* pw1  = (const float*)d_in[5];
  const float* pb1  = (const float*)d_in[6];
  const float* pw2  = (const float*)d_in[7];
  const float* pb2  = (const float*)d_in[8];
  const float* Wq   = (const float*)d_in[9];
  const float* bq   = (const float*)d_in[10];
  const float* Wk   = (const float*)d_in[11];
  const float* bk   = (const float*)d_in[12];
  const float* Wv   = (const float*)d_in[13];
  const float* bv   = (const float*)d_in[14];
  const float* Wo   = (const float*)d_in[15];
  const float* bo   = (const float*)d_in[16];
  const float* ln1s = (const float*)d_in[17];
  const float* ln1b = (const float*)d_in[18];
  const float* W1   = (const float*)d_in[19];
  const float* b1   = (const float*)d_in[20];
  const float* W2   = (const float*)d_in[21];
  const float* b2   = (const float*)d_in[22];
  const float* ln2s = (const float*)d_in[23];
  const float* ln2b = (const float*)d_in[24];
  const float* hw1  = (const float*)d_in[25];
  const float* hb1  = (const float*)d_in[26];
  const float* hw2  = (const float*)d_in[27];
  const float* hb2  = (const float*)d_in[28];
  float* out = (float*)d_out;

  float* x  = (float*)d_ws;            // 4096*256 f32
  float* y  = x  + (size_t)TOK_ * D_;
  float* qb = y  + (size_t)TOK_ * D_;  // region reused: qb16 + kb16 (bf16)
  float* kb = qb + (size_t)TOK_ * D_;  // region reused: vt16 (bf16)
  float* vb = kb + (size_t)TOK_ * D_;  // V fp32
  float* ob = vb + (size_t)TOK_ * D_;
  float* ff = ob + (size_t)TOK_ * D_;  // 4096*512
  float* lt = ff + (size_t)TOK_ * FF_; // 4096*50

  short* qb16 = (short*)qb;
  short* kb16 = qb16 + (size_t)TOK_ * D_;
  short* vt16 = (short*)kb;

  embed_kernel<<<TOK_, 128, 0, stream>>>(xyz, ew1, eb1, ew2, eb2, pw1, pb1, pw2, pb2, x);

  dim3 gQKV(12, TOK_ / 32);       // (12, 128)
  dim3 gD(D_ / 64, TOK_ / 32);    // (4, 128)
  dim3 gF(FF_ / 64, TOK_ / 32);   // (8, 128)
  for (int l = 0; l < L_; ++l) {
    const float* wq = Wq + (size_t)l * D_ * D_;
    const float* wk = Wk + (size_t)l * D_ * D_;
    const float* wv = Wv + (size_t)l * D_ * D_;
    const float* wo = Wo + (size_t)l * D_ * D_;
    ln_kernel<<<TOK_ / 4, 256, 0, stream>>>(x, ln1s + l * D_, ln1b + l * D_, y);
    qkv_mfma<<<gQKV, 256, 0, stream>>>(y, wq, wk, wv, bq + l * D_, bk + l * D_, bv + l * D_, qb16, kb16, vb);
    vtrans_kernel<<<512, 256, 0, stream>>>(vb, vt16);
    attn_mfma_kernel<<<512, 256, 0, stream>>>(qb16, kb16, vt16, ob);
    gemm_mfma<0, 1><<<gD, 256, 0, stream>>>(ob, wo, bo + l * D_, x, x, D_, D_);
    ln_kernel<<<TOK_ / 4, 256, 0, stream>>>(x, ln2s + l * D_, ln2b + l * D_, y);
    gemm_mfma<2, 0><<<gF, 256, 0, stream>>>(y, W1 + (size_t)l * D_ * FF_, b1 + l * FF_, nullptr, ff, D_, FF_);
    gemm_mfma<0, 1><<<gD, 256, 0, stream>>>(ff, W2 + (size_t)l * FF_ * D_, b2 + l * D_, x, x, FF_, D_);
  }
  gemm_mfma<1, 0><<<dim3(HHID_ / 64, TOK_ / 32), 256, 0, stream>>>(x, hw1, hb1, nullptr, y, D_, HHID_);
  gemm_kernel<0, 0><<<dim3(1, TOK_ / 64), 256, 0, stream>>>(y, hw2, hb2, nullptr, lt, HHID_, C_);
  knn_kernel<<<512, 512, 0, stream>>>(xyz, lt, out);
}

// Round 7
// 436.566 us; speedup vs baseline: 1.3091x; 1.3091x over previous
//
#include <hip/hip_runtime.h>
#include <hip/hip_bf16.h>
#include <math.h>

#define B_ 2
#define N_ 16384
#define M_ 2048
#define D_ 256
#define NHEAD_ 8
#define DH_ 32
#define FF_ 512
#define C_ 50
#define HID_ 128
#define HHID_ 256
#define L_ 4
#define EPS_ 1e-5f
#define TOK_ (B_*M_)   // 4096
// (1/sqrt(32)) * log2(e): folds softmax scale AND exp->exp2 into Q
#define QSCALE_ 0.25507604155757994f

typedef short short8 __attribute__((ext_vector_type(8)));
typedef float f32x4 __attribute__((ext_vector_type(4)));

__device__ __forceinline__ short f2bf(float f) {
  union { float f; unsigned u; } c; c.f = f;
  unsigned u = c.u;
  unsigned r = (u + 0x7FFFu + ((u >> 16) & 1u)) >> 16;
  return (short)r;
}
__device__ __forceinline__ unsigned pack2bf(float a, float b) {
  return ((unsigned)(unsigned short)f2bf(a)) | (((unsigned)(unsigned short)f2bf(b)) << 16);
}
__device__ __forceinline__ float fast_exp2(float x) {
  float r;
  asm("v_exp_f32 %0, %1" : "=v"(r) : "v"(x));
  return r;
}
__device__ __forceinline__ unsigned cvt_pk_bf16(float lo, float hi) {
  unsigned r;
  asm("v_cvt_pk_bf16_f32 %0, %1, %2" : "=v"(r) : "v"(lo), "v"(hi));
  return r;
}

// ---------------- fused embed + pos MLP ----------------
__global__ __launch_bounds__(128) void embed_kernel(
    const float* __restrict__ xyz,
    const float* __restrict__ ew1, const float* __restrict__ eb1,
    const float* __restrict__ ew2, const float* __restrict__ eb2,
    const float* __restrict__ pw1, const float* __restrict__ pb1,
    const float* __restrict__ pw2, const float* __restrict__ pb2,
    float* __restrict__ x) {
  int t = blockIdx.x;           // 0..4095
  int b = t / M_, m = t % M_;
  const float* p = xyz + ((size_t)b * N_ + (size_t)m * 8) * 3;
  float t0 = p[0], t1 = p[1], t2 = p[2];
  __shared__ float he[HID_], hp[HID_];
  int j = threadIdx.x;          // 128 threads
  {
    float a = fmaf(t0, ew1[j], fmaf(t1, ew1[HID_ + j], fmaf(t2, ew1[2 * HID_ + j], eb1[j])));
    he[j] = fmaxf(a, 0.f);
    float c = fmaf(t0, pw1[j], fmaf(t1, pw1[HID_ + j], fmaf(t2, pw1[2 * HID_ + j], pb1[j])));
    hp[j] = fmaxf(c, 0.f);
  }
  __syncthreads();
  for (int d = j; d < D_; d += HID_) {
    float acc = eb2[d] + pb2[d];
    for (int k = 0; k < HID_; ++k) {
      acc = fmaf(he[k], ew2[k * D_ + d], acc);
      acc = fmaf(hp[k], pw2[k * D_ + d], acc);
    }
    x[(size_t)t * D_ + d] = acc;
  }
}

// ---------------- LayerNorm (4 rows/block, one wave each) ----------------
__global__ __launch_bounds__(256) void ln_kernel(
    const float* __restrict__ x, const float* __restrict__ s,
    const float* __restrict__ bb, float* __restrict__ y) {
  int r = blockIdx.x * 4 + (threadIdx.x >> 6);
  int t = threadIdx.x & 63;
  const float4* xr = (const float4*)(x + (size_t)r * D_);
  float4 v = xr[t];
  float sum = v.x + v.y + v.z + v.w;
  #pragma unroll
  for (int o = 1; o < 64; o <<= 1) sum += __shfl_xor(sum, o, 64);
  float mean = sum * (1.f / D_);
  float dx = v.x - mean, dy = v.y - mean, dz = v.z - mean, dw = v.w - mean;
  float vs = dx * dx + dy * dy + dz * dz + dw * dw;
  #pragma unroll
  for (int o = 1; o < 64; o <<= 1) vs += __shfl_xor(vs, o, 64);
  float inv = 1.0f / sqrtf(vs * (1.f / D_) + EPS_);
  float4 sv = ((const float4*)s)[t];
  float4 bv = ((const float4*)bb)[t];
  float4 out;
  out.x = dx * inv * sv.x + bv.x;
  out.y = dy * inv * sv.y + bv.y;
  out.z = dz * inv * sv.z + bv.z;
  out.w = dw * inv * sv.w + bv.w;
  ((float4*)(y + (size_t)r * D_))[t] = out;
}

// ---------------- fp32 tiled GEMM (kept for head2, N=50) ----------------
template <int ACT, int RES>
__global__ __launch_bounds__(256) void gemm_kernel(
    const float* __restrict__ A, const float* __restrict__ W,
    const float* __restrict__ bias, const float* __restrict__ R,
    float* __restrict__ Cc, int K, int Ncols) {
  __shared__ float As[16][68];
  __shared__ float Ws[16][68];
  int m0 = blockIdx.y * 64;
  int n0 = blockIdx.x * 64;
  int tid = threadIdx.x;  // 256
  int tx = tid & 15, ty = tid >> 4;
  float acc[4][4] = {};
  for (int kk = 0; kk < K; kk += 16) {
    for (int i = tid; i < 64 * 16; i += 256) {
      int mm = i >> 4, kq = i & 15;
      As[kq][mm] = A[(size_t)(m0 + mm) * K + kk + kq];
    }
    for (int i = tid; i < 16 * 64; i += 256) {
      int kq = i >> 6, nn = i & 63;
      int n = n0 + nn;
      Ws[kq][nn] = (n < Ncols) ? W[(size_t)(kk + kq) * Ncols + n] : 0.f;
    }
    __syncthreads();
    #pragma unroll
    for (int kq = 0; kq < 16; ++kq) {
      float a[4], w[4];
      #pragma unroll
      for (int i = 0; i < 4; ++i) a[i] = As[kq][ty * 4 + i];
      #pragma unroll
      for (int jj = 0; jj < 4; ++jj) w[jj] = Ws[kq][tx * 4 + jj];
      #pragma unroll
      for (int i = 0; i < 4; ++i)
        #pragma unroll
        for (int jj = 0; jj < 4; ++jj) acc[i][jj] = fmaf(a[i], w[jj], acc[i][jj]);
    }
    __syncthreads();
  }
  #pragma unroll
  for (int i = 0; i < 4; ++i) {
    int m = m0 + ty * 4 + i;
    #pragma unroll
    for (int jj = 0; jj < 4; ++jj) {
      int n = n0 + tx * 4 + jj;
      if (n >= Ncols) continue;
      float v = acc[i][jj] + bias[n];
      if (ACT == 1) v = fmaxf(v, 0.f);
      else if (ACT == 2) v = 0.5f * v * (1.f + erff(v * 0.70710678118654752f));
      if (RES) v += R[(size_t)m * Ncols + n];
      Cc[(size_t)m * Ncols + n] = v;
    }
  }
}

// ---------------- bf16 MFMA GEMM: BM=32, BN=64, BK=32, 4 waves (16x32 each) ----------------
template <int ACT, int RES>
__device__ __forceinline__ void gemm_body(
    const float* __restrict__ A, const float* __restrict__ W,
    const float* __restrict__ bias, const float* __restrict__ R,
    float* __restrict__ Cc, short* __restrict__ out16, float oscale,
    int K, int Ncols, int m0, int n0) {
  __shared__ short As[32][40];
  __shared__ short Bs[64][40];
  int tid = threadIdx.x;
  int w = tid >> 6, l = tid & 63;
  int lq = l & 15, lg = l >> 4;
  int wr = (w & 1) * 16, wc = (w >> 1) * 32;
  int ar = tid >> 3, ak = (tid & 7) * 4;
  int wn = tid & 63, wk = (tid >> 6) * 8;
  f32x4 acc0 = {0.f, 0.f, 0.f, 0.f};
  f32x4 acc1 = {0.f, 0.f, 0.f, 0.f};
  for (int kk = 0; kk < K; kk += 32) {
    __syncthreads();
    {
      float4 a4 = *(const float4*)(A + (size_t)(m0 + ar) * K + kk + ak);
      uint2 au;
      au.x = pack2bf(a4.x, a4.y);
      au.y = pack2bf(a4.z, a4.w);
      *(uint2*)&As[ar][ak] = au;
      const float* wp = W + (size_t)(kk + wk) * Ncols + n0 + wn;
      float w0 = wp[0];
      float w1 = wp[(size_t)Ncols];
      float w2 = wp[2 * (size_t)Ncols];
      float w3 = wp[3 * (size_t)Ncols];
      float w4 = wp[4 * (size_t)Ncols];
      float w5 = wp[5 * (size_t)Ncols];
      float w6 = wp[6 * (size_t)Ncols];
      float w7 = wp[7 * (size_t)Ncols];
      uint4 wu;
      wu.x = pack2bf(w0, w1); wu.y = pack2bf(w2, w3);
      wu.z = pack2bf(w4, w5); wu.w = pack2bf(w6, w7);
      *(uint4*)&Bs[wn][wk] = wu;
    }
    __syncthreads();
    short8 af = *(short8*)&As[wr + lq][lg * 8];
    short8 b0 = *(short8*)&Bs[wc + lq][lg * 8];
    short8 b1 = *(short8*)&Bs[wc + 16 + lq][lg * 8];
    acc0 = __builtin_amdgcn_mfma_f32_16x16x32_bf16(af, b0, acc0, 0, 0, 0);
    acc1 = __builtin_amdgcn_mfma_f32_16x16x32_bf16(af, b1, acc1, 0, 0, 0);
  }
  int row = m0 + wr + lg * 4;
  #pragma unroll
  for (int r = 0; r < 4; ++r) {
    #pragma unroll
    for (int fj = 0; fj < 2; ++fj) {
      int col = n0 + wc + fj * 16 + lq;
      float v = (fj ? acc1[r] : acc0[r]) + bias[col];
      if (ACT == 1) v = fmaxf(v, 0.f);
      else if (ACT == 2) v = 0.5f * v * (1.f + erff(v * 0.70710678118654752f));
      if (RES) v += R[(size_t)(row + r) * Ncols + col];
      if (out16) out16[(size_t)(row + r) * Ncols + col] = f2bf(v * oscale);
      else Cc[(size_t)(row + r) * Ncols + col] = v;
    }
  }
}

template <int ACT, int RES>
__global__ __launch_bounds__(256) void gemm_mfma(
    const float* __restrict__ A, const float* __restrict__ W,
    const float* __restrict__ bias, const float* __restrict__ R,
    float* __restrict__ Cc, int K, int Ncols) {
  gemm_body<ACT, RES>(A, W, bias, R, Cc, nullptr, 1.f, K, Ncols, blockIdx.y * 32, blockIdx.x * 64);
}

// Q -> bf16 (scaled by QSCALE_), K -> bf16, V -> fp32
__global__ __launch_bounds__(256) void qkv_mfma(
    const float* __restrict__ A,
    const float* __restrict__ Wq, const float* __restrict__ Wk, const float* __restrict__ Wv,
    const float* __restrict__ bq, const float* __restrict__ bk, const float* __restrict__ bv,
    short* __restrict__ q16, short* __restrict__ k16, float* __restrict__ vb) {
  int sel = blockIdx.x >> 2;
  int n0 = (blockIdx.x & 3) << 6;
  const float* W = sel == 0 ? Wq : (sel == 1 ? Wk : Wv);
  const float* bb = sel == 0 ? bq : (sel == 1 ? bk : bv);
  short* out16 = sel == 0 ? q16 : (sel == 1 ? k16 : nullptr);
  float oscale = sel == 0 ? QSCALE_ : 1.f;
  gemm_body<0, 0>(A, W, bb, nullptr, vb, out16, oscale, D_, D_, blockIdx.y * 32, n0);
}

// ---------------- V transpose: vb fp32 [tok][256] -> vt16 bf16 [b][h][32][2048] ----------------
__global__ __launch_bounds__(256) void vtrans_kernel(
    const float* __restrict__ vb, short* __restrict__ vt16) {
  int bid = blockIdx.x;
  int mt = bid & 31;
  int h = (bid >> 5) & 7;
  int b = bid >> 8;
  __shared__ short ts[64][34];
  int m0 = mt * 64;
  int tid = threadIdx.x;
  int mm = tid >> 2, dd = (tid & 3) * 8;
  const float* vp = vb + (size_t)(b * M_ + m0 + mm) * D_ + h * DH_ + dd;
  float4 a0 = ((const float4*)vp)[0];
  float4 a1 = ((const float4*)vp)[1];
  ts[mm][dd + 0] = f2bf(a0.x); ts[mm][dd + 1] = f2bf(a0.y);
  ts[mm][dd + 2] = f2bf(a0.z); ts[mm][dd + 3] = f2bf(a0.w);
  ts[mm][dd + 4] = f2bf(a1.x); ts[mm][dd + 5] = f2bf(a1.y);
  ts[mm][dd + 6] = f2bf(a1.z); ts[mm][dd + 7] = f2bf(a1.w);
  __syncthreads();
  int d = tid >> 3, mc = (tid & 7) * 8;
  short8 r;
  #pragma unroll
  for (int j = 0; j < 8; ++j) r[j] = ts[mc + j][d];
  *(short8*)&vt16[(size_t)((b * NHEAD_ + h) * DH_ + d) * M_ + m0 + mc] = r;
}

// ---------------- flash attention: no-max exp2 softmax, KV-split x2 ----------------
// grid: 1024 = b(2) x h(8) x qt(32) x half(2); 256 thr = 4 waves x 16 q-rows
// partials: po[half][f][32] (unnormalized O), pl[half][f] (sum of exp2)
#define KSTR 40
#define VSTR 72
#define PSTR 72
__global__ __launch_bounds__(256) void attn_mfma_kernel(
    const short* __restrict__ q16, const short* __restrict__ k16,
    const short* __restrict__ vt16, float* __restrict__ po, float* __restrict__ pl) {
  __shared__ short Ks[64][KSTR];
  __shared__ short Vt[32][VSTR];
  __shared__ short Ps[4][16][PSTR];
  int bid = blockIdx.x;
  int half = bid & 1;
  int qt = (bid >> 1) & 31;
  int h  = (bid >> 6) & 7;
  int b  = bid >> 9;
  int tid = threadIdx.x;
  int w  = tid >> 6;
  int l  = tid & 63;
  int lq = l & 15;
  int lg = l >> 4;

  // Q frag: bf16, pre-scaled (log2-domain)
  short8 qf = *(const short8*)&q16[(size_t)(b * M_ + qt * 64 + w * 16 + lq) * D_ + h * DH_ + lg * 8];

  float l_i = 0.f;
  f32x4 o0 = {0.f, 0.f, 0.f, 0.f};   // O^T: d = lg*4+r,      q-col = lq
  f32x4 o1 = {0.f, 0.f, 0.f, 0.f};   // O^T: d = 16 + lg*4+r, q-col = lq
  int srow = tid >> 2, scol = (tid & 3) * 8;     // K staging
  int vd = tid >> 3, vm = (tid & 7) * 8;         // V^T staging
  const short* kp = k16 + (size_t)(b * M_ + half * 1024 + srow) * D_ + h * DH_ + scol;
  const short* vp = vt16 + (size_t)((b * NHEAD_ + h) * DH_ + vd) * M_ + half * 1024 + vm;

  for (int kt = 0; kt < 16; ++kt) {
    __syncthreads();
    *(short8*)&Ks[srow][scol] = *(const short8*)(kp + (size_t)(kt * 64) * D_);
    *(short8*)&Vt[vd][vm]     = *(const short8*)(vp + kt * 64);
    __syncthreads();
    // S'^T[kv][q] = K-tile · Q^T (log2-domain), then P = exp2(S') raw (no max)
    f32x4 st[4];
    #pragma unroll
    for (int t = 0; t < 4; ++t) {
      short8 kf = *(short8*)&Ks[t * 16 + lq][lg * 8];
      f32x4 z = {0.f, 0.f, 0.f, 0.f};
      st[t] = __builtin_amdgcn_mfma_f32_16x16x32_bf16(kf, qf, z, 0, 0, 0);
    }
    #pragma unroll
    for (int t = 0; t < 4; ++t)
      #pragma unroll
      for (int r2 = 0; r2 < 4; ++r2) {
        st[t][r2] = fast_exp2(st[t][r2]);
        l_i += st[t][r2];
      }
    // pack P (bf16) into per-wave LDS: Ps[w][q][kv] (wave-synchronous, no barrier)
    {
      unsigned* pw = (unsigned*)&Ps[w][lq][0];
      #pragma unroll
      for (int t = 0; t < 4; ++t) {
        uint2 pk;
        pk.x = cvt_pk_bf16(st[t][0], st[t][1]);
        pk.y = cvt_pk_bf16(st[t][2], st[t][3]);
        *(uint2*)(pw + t * 8 + lg * 2) = pk;
      }
    }
    // O^T += V^T · P
    #pragma unroll
    for (int c = 0; c < 2; ++c) {
      short8 pf = *(short8*)&Ps[w][lq][c * 32 + lg * 8];
      short8 v0 = *(short8*)&Vt[lq][c * 32 + lg * 8];
      short8 v1 = *(short8*)&Vt[16 + lq][c * 32 + lg * 8];
      o0 = __builtin_amdgcn_mfma_f32_16x16x32_bf16(v0, pf, o0, 0, 0, 0);
      o1 = __builtin_amdgcn_mfma_f32_16x16x32_bf16(v1, pf, o1, 0, 0, 0);
    }
  }
  // reduce l over lane groups (kv quarters)
  l_i += __shfl_xor(l_i, 16, 64);
  l_i += __shfl_xor(l_i, 32, 64);
  int f = (b * NHEAD_ + h) * M_ + qt * 64 + w * 16 + lq;
  float* pp = po + ((size_t)half * (16 * M_) + f) * 32;
  #pragma unroll
  for (int r2 = 0; r2 < 4; ++r2) pp[lg * 4 + r2] = o0[r2];
  #pragma unroll
  for (int r2 = 0; r2 < 4; ++r2) pp[16 + lg * 4 + r2] = o1[r2];
  if (lg == 0) pl[half * (16 * M_) + f] = l_i;
}

// combine: out = (po0 + po1) / (l0 + l1), scatter to [b][m][h*32+d]
__global__ __launch_bounds__(256) void attn_combine(
    const float* __restrict__ po, const float* __restrict__ pl,
    float* __restrict__ o) {
  int idx = blockIdx.x * 256 + threadIdx.x;   // 0..262143
  int f = idx >> 3, dq = (idx & 7) * 4;
  float inv = 1.f / (pl[f] + pl[16 * M_ + f]);
  const float4 a = *(const float4*)&po[(size_t)f * 32 + dq];
  const float4 c = *(const float4*)&po[(size_t)(16 * M_ + f) * 32 + dq];
  int b = f >> 14, h = (f >> 11) & 7, m = f & (M_ - 1);
  float4 r;
  r.x = (a.x + c.x) * inv;
  r.y = (a.y + c.y) * inv;
  r.z = (a.z + c.z) * inv;
  r.w = (a.w + c.w) * inv;
  *(float4*)&o[(size_t)(b * M_ + m) * D_ + h * DH_ + dq] = r;
}

// ---------------- KNN top-3 + gather/mean ----------------
__global__ __launch_bounds__(512) void knn_kernel(
    const float* __restrict__ xyz, const float* __restrict__ lt,
    float* __restrict__ out) {
  __shared__ float4 tok[2056];   // 2048 + 8 pad
  int b = blockIdx.x >> 8;                  // 256 blocks per batch
  int q0 = (blockIdx.x & 255) << 6;         // 64 queries per block
  int tid = threadIdx.x;
  for (int i = tid; i < M_; i += 512) {
    const float* tp = xyz + ((size_t)b * N_ + (size_t)i * 8) * 3;
    float a = tp[0], bb = tp[1], cc = tp[2];
    tok[i + (i >> 8)] = make_float4(a, bb, cc, a * a + bb * bb + cc * cc);
  }
  __syncthreads();
  int qi = tid >> 3, sl = tid & 7;
  int n = q0 + qi;
  const float* qp = xyz + ((size_t)b * N_ + n) * 3;
  float qx = qp[0], qy = qp[1], qz = qp[2];
  float q2 = qx * qx + qy * qy + qz * qz;
  float dd0 = INFINITY, dd1 = INFINITY, dd2 = INFINITY;
  int ii0 = 0, ii1 = 0, ii2 = 0;
  const float4* cp = &tok[sl * 257];
  int mb = sl << 8;
  #pragma unroll 4
  for (int j = 0; j < 256; ++j) {
    float4 t = cp[j];
    float dot = fmaf(qx, t.x, fmaf(qy, t.y, qz * t.z));
    float d = fmaxf(q2 + t.w - 2.f * dot, 0.f);
    if (d < dd2) {
      int m = mb + j;
      if (d < dd1) {
        dd2 = dd1; ii2 = ii1;
        if (d < dd0) { dd1 = dd0; ii1 = ii0; dd0 = d; ii0 = m; }
        else         { dd1 = d;  ii1 = m; }
      } else         { dd2 = d;  ii2 = m; }
    }
  }
  auto insT = [&](float d, int i) {
    if (d < dd2 || (d == dd2 && i < ii2)) {
      if (d < dd1 || (d == dd1 && i < ii1)) {
        dd2 = dd1; ii2 = ii1;
        if (d < dd0 || (d == dd0 && i < ii0)) { dd1 = dd0; ii1 = ii0; dd0 = d; ii0 = i; }
        else { dd1 = d; ii1 = i; }
      } else { dd2 = d; ii2 = i; }
    }
  };
  #pragma unroll
  for (int off = 1; off < 8; off <<= 1) {
    float pd0 = __shfl_xor(dd0, off, 64); int pi0 = __shfl_xor(ii0, off, 64);
    float pd1 = __shfl_xor(dd1, off, 64); int pi1 = __shfl_xor(ii1, off, 64);
    float pd2 = __shfl_xor(dd2, off, 64); int pi2 = __shfl_xor(ii2, off, 64);
    insT(pd0, pi0); insT(pd1, pi1); insT(pd2, pi2);
  }
  const float* l0 = lt + ((size_t)b * M_ + ii0) * C_;
  const float* l1 = lt + ((size_t)b * M_ + ii1) * C_;
  const float* l2 = lt + ((size_t)b * M_ + ii2) * C_;
  float* op = out + ((size_t)b * N_ + n) * C_;
  for (int cc = sl; cc < C_; cc += 8)
    op[cc] = (l0[cc] + l1[cc] + l2[cc]) * (1.f / 3.f);
}

extern "C" void kernel_launch(void* const* d_in, const int* in_sizes, int n_in,
                              void* d_out, int out_size, void* d_ws, size_t ws_size,
                              hipStream_t stream) {
  const float* xyz  = (const float*)d_in[0];
  const float* ew1  = (const float*)d_in[1];
  const float* eb1  = (const float*)d_in[2];
  const float* ew2  = (const float*)d_in[3];
  const float* eb2  = (const float*)d_in[4];
  const float* pw1  = (const float*)d_in[5];
  const float* pb1  = (const float*)d_in[6];
  const float* pw2  = (const float*)d_in[7];
  const float* pb2  = (const float*)d_in[8];
  const float* Wq   = (const float*)d_in[9];
  const float* bq   = (const float*)d_in[10];
  const float* Wk   = (const float*)d_in[11];
  const float* bk   = (const float*)d_in[12];
  const float* Wv   = (const float*)d_in[13];
  const float* bv   = (const float*)d_in[14];
  const float* Wo   = (const float*)d_in[15];
  const float* bo   = (const float*)d_in[16];
  const float* ln1s = (const float*)d_in[17];
  const float* ln1b = (const float*)d_in[18];
  const float* W1   = (const float*)d_in[19];
  const float* b1   = (const float*)d_in[20];
  const float* W2   = (const float*)d_in[21];
  const float* b2   = (const float*)d_in[22];
  const float* ln2s = (const float*)d_in[23];
  const float* ln2b = (const float*)d_in[24];
  const float* hw1  = (const float*)d_in[25];
  const float* hb1  = (const float*)d_in[26];
  const float* hw2  = (const float*)d_in[27];
  const float* hb2  = (const float*)d_in[28];
  float* out = (float*)d_out;

  float* x  = (float*)d_ws;            // 4096*256 f32
  float* y  = x  + (size_t)TOK_ * D_;
  float* qb = y  + (size_t)TOK_ * D_;  // region reused: qb16 + kb16 (bf16)
  float* kb = qb + (size_t)TOK_ * D_;  // region reused: vt16 (bf16)
  float* vb = kb + (size_t)TOK_ * D_;  // V fp32
  float* ob = vb + (size_t)TOK_ * D_;
  float* ff = ob + (size_t)TOK_ * D_;  // 4096*512 (reused as attn O partials)
  float* lt = ff + (size_t)TOK_ * FF_; // 4096*50  (reused as attn l partials)

  short* qb16 = (short*)qb;
  short* kb16 = qb16 + (size_t)TOK_ * D_;
  short* vt16 = (short*)kb;
  float* po = ff;   // 2 x 32768 x 32 floats = 2,097,152 = ff size
  float* pl = lt;   // 2 x 32768 floats

  embed_kernel<<<TOK_, 128, 0, stream>>>(xyz, ew1, eb1, ew2, eb2, pw1, pb1, pw2, pb2, x);

  dim3 gQKV(12, TOK_ / 32);       // (12, 128)
  dim3 gD(D_ / 64, TOK_ / 32);    // (4, 128)
  dim3 gF(FF_ / 64, TOK_ / 32);   // (8, 128)
  for (int l = 0; l < L_; ++l) {
    const float* wq = Wq + (size_t)l * D_ * D_;
    const float* wk = Wk + (size_t)l * D_ * D_;
    const float* wv = Wv + (size_t)l * D_ * D_;
    const float* wo = Wo + (size_t)l * D_ * D_;
    ln_kernel<<<TOK_ / 4, 256, 0, stream>>>(x, ln1s + l * D_, ln1b + l * D_, y);
    qkv_mfma<<<gQKV, 256, 0, stream>>>(y, wq, wk, wv, bq + l * D_, bk + l * D_, bv + l * D_, qb16, kb16, vb);
    vtrans_kernel<<<512, 256, 0, stream>>>(vb, vt16);
    attn_mfma_kernel<<<1024, 256, 0, stream>>>(qb16, kb16, vt16, po, pl);
    attn_combine<<<1024, 256, 0, stream>>>(po, pl, ob);
    gemm_mfma<0, 1><<<gD, 256, 0, stream>>>(ob, wo, bo + l * D_, x, x, D_, D_);
    ln_kernel<<<TOK_ / 4, 256, 0, stream>>>(x, ln2s + l * D_, ln2b + l * D_, y);
    gemm_mfma<2, 0><<<gF, 256, 0, stream>>>(y, W1 + (size_t)l * D_ * FF_, b1 + l * FF_, nullptr, ff, D_, FF_);
    gemm_mfma<0, 1><<<gD, 256, 0, stream>>>(ff, W2 + (size_t)l * FF_ * D_, b2 + l * D_, x, x, FF_, D_);
  }
  gemm_mfma<1, 0><<<dim3(HHID_ / 64, TOK_ / 32), 256, 0, stream>>>(x, hw1, hb1, nullptr, y, D_, HHID_);
  gemm_kernel<0, 0><<<dim3(1, TOK_ / 64), 256, 0, stream>>>(y, hw2, hb2, nullptr, lt, HHID_, C_);
  knn_kernel<<<512, 512, 0, stream>>>(xyz, lt, out);
}

// Round 8
// 415.687 us; speedup vs baseline: 1.3749x; 1.0502x over previous
//
#include <hip/hip_runtime.h>
#include <hip/hip_bf16.h>
#include <math.h>

#define B_ 2
#define N_ 16384
#define M_ 2048
#define D_ 256
#define NHEAD_ 8
#define DH_ 32
#define FF_ 512
#define C_ 50
#define HID_ 128
#define HHID_ 256
#define L_ 4
#define EPS_ 1e-5f
#define TOK_ (B_*M_)   // 4096
// (1/sqrt(32)) * log2(e): folds softmax scale AND exp->exp2 into Q
#define QSCALE_ 0.25507604155757994f

typedef short short8 __attribute__((ext_vector_type(8)));
typedef float f32x4 __attribute__((ext_vector_type(4)));

__device__ __forceinline__ short f2bf(float f) {
  union { float f; unsigned u; } c; c.f = f;
  unsigned u = c.u;
  unsigned r = (u + 0x7FFFu + ((u >> 16) & 1u)) >> 16;
  return (short)r;
}
__device__ __forceinline__ unsigned pack2bf(float a, float b) {
  return ((unsigned)(unsigned short)f2bf(a)) | (((unsigned)(unsigned short)f2bf(b)) << 16);
}
__device__ __forceinline__ float fast_exp2(float x) {
  float r;
  asm("v_exp_f32 %0, %1" : "=v"(r) : "v"(x));
  return r;
}
__device__ __forceinline__ unsigned cvt_pk_bf16(float lo, float hi) {
  unsigned r;
  asm("v_cvt_pk_bf16_f32 %0, %1, %2" : "=v"(r) : "v"(lo), "v"(hi));
  return r;
}

// ---------------- fused embed + pos MLP ----------------
__global__ __launch_bounds__(128) void embed_kernel(
    const float* __restrict__ xyz,
    const float* __restrict__ ew1, const float* __restrict__ eb1,
    const float* __restrict__ ew2, const float* __restrict__ eb2,
    const float* __restrict__ pw1, const float* __restrict__ pb1,
    const float* __restrict__ pw2, const float* __restrict__ pb2,
    float* __restrict__ x) {
  int t = blockIdx.x;           // 0..4095
  int b = t / M_, m = t % M_;
  const float* p = xyz + ((size_t)b * N_ + (size_t)m * 8) * 3;
  float t0 = p[0], t1 = p[1], t2 = p[2];
  __shared__ float he[HID_], hp[HID_];
  int j = threadIdx.x;          // 128 threads
  {
    float a = fmaf(t0, ew1[j], fmaf(t1, ew1[HID_ + j], fmaf(t2, ew1[2 * HID_ + j], eb1[j])));
    he[j] = fmaxf(a, 0.f);
    float c = fmaf(t0, pw1[j], fmaf(t1, pw1[HID_ + j], fmaf(t2, pw1[2 * HID_ + j], pb1[j])));
    hp[j] = fmaxf(c, 0.f);
  }
  __syncthreads();
  for (int d = j; d < D_; d += HID_) {
    float acc = eb2[d] + pb2[d];
    for (int k = 0; k < HID_; ++k) {
      acc = fmaf(he[k], ew2[k * D_ + d], acc);
      acc = fmaf(hp[k], pw2[k * D_ + d], acc);
    }
    x[(size_t)t * D_ + d] = acc;
  }
}

// ---------------- LayerNorm (4 rows/block, one wave each) ----------------
__global__ __launch_bounds__(256) void ln_kernel(
    const float* __restrict__ x, const float* __restrict__ s,
    const float* __restrict__ bb, float* __restrict__ y) {
  int r = blockIdx.x * 4 + (threadIdx.x >> 6);
  int t = threadIdx.x & 63;
  const float4* xr = (const float4*)(x + (size_t)r * D_);
  float4 v = xr[t];
  float sum = v.x + v.y + v.z + v.w;
  #pragma unroll
  for (int o = 1; o < 64; o <<= 1) sum += __shfl_xor(sum, o, 64);
  float mean = sum * (1.f / D_);
  float dx = v.x - mean, dy = v.y - mean, dz = v.z - mean, dw = v.w - mean;
  float vs = dx * dx + dy * dy + dz * dz + dw * dw;
  #pragma unroll
  for (int o = 1; o < 64; o <<= 1) vs += __shfl_xor(vs, o, 64);
  float inv = 1.0f / sqrtf(vs * (1.f / D_) + EPS_);
  float4 sv = ((const float4*)s)[t];
  float4 bv = ((const float4*)bb)[t];
  float4 out;
  out.x = dx * inv * sv.x + bv.x;
  out.y = dy * inv * sv.y + bv.y;
  out.z = dz * inv * sv.z + bv.z;
  out.w = dw * inv * sv.w + bv.w;
  ((float4*)(y + (size_t)r * D_))[t] = out;
}

// ---------------- head2: one wave per token, lane = output class ----------------
__global__ __launch_bounds__(256) void head2_kernel(
    const float* __restrict__ y, const float* __restrict__ w2,
    const float* __restrict__ b2, float* __restrict__ lt) {
  __shared__ float ys[4][HHID_];
  int w = threadIdx.x >> 6, l = threadIdx.x & 63;
  int t = blockIdx.x * 4 + w;
  float4 v = ((const float4*)(y + (size_t)t * HHID_))[l];
  *(float4*)&ys[w][l * 4] = v;
  int c = l < C_ ? l : 0;
  float a0 = 0.f, a1 = 0.f, a2 = 0.f, a3 = 0.f;
  #pragma unroll 4
  for (int k = 0; k < HHID_; k += 4) {
    a0 = fmaf(ys[w][k + 0], w2[(k + 0) * C_ + c], a0);
    a1 = fmaf(ys[w][k + 1], w2[(k + 1) * C_ + c], a1);
    a2 = fmaf(ys[w][k + 2], w2[(k + 2) * C_ + c], a2);
    a3 = fmaf(ys[w][k + 3], w2[(k + 3) * C_ + c], a3);
  }
  if (l < C_) lt[(size_t)t * C_ + l] = (a0 + a1) + (a2 + a3) + b2[l];
}

// ---------------- bf16 MFMA GEMM: BM=32, BN=64, BK=32, 4 waves (16x32 each) ----------------
template <int ACT, int RES>
__device__ __forceinline__ void gemm_body(
    const float* __restrict__ A, const float* __restrict__ W,
    const float* __restrict__ bias, const float* __restrict__ R,
    float* __restrict__ Cc, short* __restrict__ out16, float oscale,
    int K, int Ncols, int m0, int n0) {
  __shared__ short As[32][40];
  __shared__ short Bs[64][40];
  int tid = threadIdx.x;
  int w = tid >> 6, l = tid & 63;
  int lq = l & 15, lg = l >> 4;
  int wr = (w & 1) * 16, wc = (w >> 1) * 32;
  int ar = tid >> 3, ak = (tid & 7) * 4;
  int wn = tid & 63, wk = (tid >> 6) * 8;
  f32x4 acc0 = {0.f, 0.f, 0.f, 0.f};
  f32x4 acc1 = {0.f, 0.f, 0.f, 0.f};
  for (int kk = 0; kk < K; kk += 32) {
    __syncthreads();
    {
      float4 a4 = *(const float4*)(A + (size_t)(m0 + ar) * K + kk + ak);
      uint2 au;
      au.x = pack2bf(a4.x, a4.y);
      au.y = pack2bf(a4.z, a4.w);
      *(uint2*)&As[ar][ak] = au;
      const float* wp = W + (size_t)(kk + wk) * Ncols + n0 + wn;
      float w0 = wp[0];
      float w1 = wp[(size_t)Ncols];
      float w2 = wp[2 * (size_t)Ncols];
      float w3 = wp[3 * (size_t)Ncols];
      float w4 = wp[4 * (size_t)Ncols];
      float w5 = wp[5 * (size_t)Ncols];
      float w6 = wp[6 * (size_t)Ncols];
      float w7 = wp[7 * (size_t)Ncols];
      uint4 wu;
      wu.x = pack2bf(w0, w1); wu.y = pack2bf(w2, w3);
      wu.z = pack2bf(w4, w5); wu.w = pack2bf(w6, w7);
      *(uint4*)&Bs[wn][wk] = wu;
    }
    __syncthreads();
    short8 af = *(short8*)&As[wr + lq][lg * 8];
    short8 b0 = *(short8*)&Bs[wc + lq][lg * 8];
    short8 b1 = *(short8*)&Bs[wc + 16 + lq][lg * 8];
    acc0 = __builtin_amdgcn_mfma_f32_16x16x32_bf16(af, b0, acc0, 0, 0, 0);
    acc1 = __builtin_amdgcn_mfma_f32_16x16x32_bf16(af, b1, acc1, 0, 0, 0);
  }
  int row = m0 + wr + lg * 4;
  #pragma unroll
  for (int r = 0; r < 4; ++r) {
    #pragma unroll
    for (int fj = 0; fj < 2; ++fj) {
      int col = n0 + wc + fj * 16 + lq;
      float v = (fj ? acc1[r] : acc0[r]) + bias[col];
      if (ACT == 1) v = fmaxf(v, 0.f);
      else if (ACT == 2) v = 0.5f * v * (1.f + erff(v * 0.70710678118654752f));
      if (RES) v += R[(size_t)(row + r) * Ncols + col];
      if (out16) out16[(size_t)(row + r) * Ncols + col] = f2bf(v * oscale);
      else Cc[(size_t)(row + r) * Ncols + col] = v;
    }
  }
}

template <int ACT, int RES>
__global__ __launch_bounds__(256) void gemm_mfma(
    const float* __restrict__ A, const float* __restrict__ W,
    const float* __restrict__ bias, const float* __restrict__ R,
    float* __restrict__ Cc, int K, int Ncols) {
  gemm_body<ACT, RES>(A, W, bias, R, Cc, nullptr, 1.f, K, Ncols, blockIdx.y * 32, blockIdx.x * 64);
}

// Q -> bf16 (scaled by QSCALE_), K -> bf16, V -> fp32
__global__ __launch_bounds__(256) void qkv_mfma(
    const float* __restrict__ A,
    const float* __restrict__ Wq, const float* __restrict__ Wk, const float* __restrict__ Wv,
    const float* __restrict__ bq, const float* __restrict__ bk, const float* __restrict__ bv,
    short* __restrict__ q16, short* __restrict__ k16, float* __restrict__ vb) {
  int sel = blockIdx.x >> 2;
  int n0 = (blockIdx.x & 3) << 6;
  const float* W = sel == 0 ? Wq : (sel == 1 ? Wk : Wv);
  const float* bb = sel == 0 ? bq : (sel == 1 ? bk : bv);
  short* out16 = sel == 0 ? q16 : (sel == 1 ? k16 : nullptr);
  float oscale = sel == 0 ? QSCALE_ : 1.f;
  gemm_body<0, 0>(A, W, bb, nullptr, vb, out16, oscale, D_, D_, blockIdx.y * 32, n0);
}

// ---------------- V transpose: vb fp32 [tok][256] -> vt16 bf16 [b][h][32][2048] ----------------
__global__ __launch_bounds__(256) void vtrans_kernel(
    const float* __restrict__ vb, short* __restrict__ vt16) {
  int bid = blockIdx.x;
  int mt = bid & 31;
  int h = (bid >> 5) & 7;
  int b = bid >> 8;
  __shared__ short ts[64][34];
  int m0 = mt * 64;
  int tid = threadIdx.x;
  int mm = tid >> 2, dd = (tid & 3) * 8;
  const float* vp = vb + (size_t)(b * M_ + m0 + mm) * D_ + h * DH_ + dd;
  float4 a0 = ((const float4*)vp)[0];
  float4 a1 = ((const float4*)vp)[1];
  ts[mm][dd + 0] = f2bf(a0.x); ts[mm][dd + 1] = f2bf(a0.y);
  ts[mm][dd + 2] = f2bf(a0.z); ts[mm][dd + 3] = f2bf(a0.w);
  ts[mm][dd + 4] = f2bf(a1.x); ts[mm][dd + 5] = f2bf(a1.y);
  ts[mm][dd + 6] = f2bf(a1.z); ts[mm][dd + 7] = f2bf(a1.w);
  __syncthreads();
  int d = tid >> 3, mc = (tid & 7) * 8;
  short8 r;
  #pragma unroll
  for (int j = 0; j < 8; ++j) r[j] = ts[mc + j][d];
  *(short8*)&vt16[(size_t)((b * NHEAD_ + h) * DH_ + d) * M_ + m0 + mc] = r;
}

// ---------------- flash attention: no-max exp2 softmax, KV-split x4 ----------------
// grid: 2048 = b(2) x h(8) x qt(32) x quarter(4); 256 thr = 4 waves x 16 q-rows
// partials: po_q[quarter] -> [f][32] unnormalized O; pl[quarter*32768+f] = sum exp2
#define KSTR 40
#define VSTR 72
#define PSTR 72
__global__ __launch_bounds__(256) void attn_mfma_kernel(
    const short* __restrict__ q16, const short* __restrict__ k16,
    const short* __restrict__ vt16,
    float* __restrict__ po0, float* __restrict__ po1,
    float* __restrict__ po2, float* __restrict__ po3,
    float* __restrict__ pl) {
  __shared__ short Ks[64][KSTR];
  __shared__ short Vt[32][VSTR];
  __shared__ short Ps[4][16][PSTR];
  int bid = blockIdx.x;
  int quar = bid & 3;
  int qt = (bid >> 2) & 31;
  int h  = (bid >> 7) & 7;
  int b  = bid >> 10;
  int tid = threadIdx.x;
  int w  = tid >> 6;
  int l  = tid & 63;
  int lq = l & 15;
  int lg = l >> 4;

  // Q frag: bf16, pre-scaled (log2-domain)
  short8 qf = *(const short8*)&q16[(size_t)(b * M_ + qt * 64 + w * 16 + lq) * D_ + h * DH_ + lg * 8];

  float l_i = 0.f;
  f32x4 o0 = {0.f, 0.f, 0.f, 0.f};   // O^T: d = lg*4+r,      q-col = lq
  f32x4 o1 = {0.f, 0.f, 0.f, 0.f};   // O^T: d = 16 + lg*4+r, q-col = lq
  int srow = tid >> 2, scol = (tid & 3) * 8;     // K staging
  int vd = tid >> 3, vm = (tid & 7) * 8;         // V^T staging
  const short* kp = k16 + (size_t)(b * M_ + quar * 512 + srow) * D_ + h * DH_ + scol;
  const short* vp = vt16 + (size_t)((b * NHEAD_ + h) * DH_ + vd) * M_ + quar * 512 + vm;

  for (int kt = 0; kt < 8; ++kt) {
    __syncthreads();
    *(short8*)&Ks[srow][scol] = *(const short8*)(kp + (size_t)(kt * 64) * D_);
    *(short8*)&Vt[vd][vm]     = *(const short8*)(vp + kt * 64);
    __syncthreads();
    // S'^T[kv][q] = K-tile · Q^T (log2-domain), then P = exp2(S') raw (no max)
    f32x4 st[4];
    #pragma unroll
    for (int t = 0; t < 4; ++t) {
      short8 kf = *(short8*)&Ks[t * 16 + lq][lg * 8];
      f32x4 z = {0.f, 0.f, 0.f, 0.f};
      st[t] = __builtin_amdgcn_mfma_f32_16x16x32_bf16(kf, qf, z, 0, 0, 0);
    }
    #pragma unroll
    for (int t = 0; t < 4; ++t)
      #pragma unroll
      for (int r2 = 0; r2 < 4; ++r2) {
        st[t][r2] = fast_exp2(st[t][r2]);
        l_i += st[t][r2];
      }
    // pack P (bf16) into per-wave LDS: Ps[w][q][kv] (wave-synchronous, no barrier)
    {
      unsigned* pw = (unsigned*)&Ps[w][lq][0];
      #pragma unroll
      for (int t = 0; t < 4; ++t) {
        uint2 pk;
        pk.x = cvt_pk_bf16(st[t][0], st[t][1]);
        pk.y = cvt_pk_bf16(st[t][2], st[t][3]);
        *(uint2*)(pw + t * 8 + lg * 2) = pk;
      }
    }
    // O^T += V^T · P
    #pragma unroll
    for (int c = 0; c < 2; ++c) {
      short8 pf = *(short8*)&Ps[w][lq][c * 32 + lg * 8];
      short8 v0 = *(short8*)&Vt[lq][c * 32 + lg * 8];
      short8 v1 = *(short8*)&Vt[16 + lq][c * 32 + lg * 8];
      o0 = __builtin_amdgcn_mfma_f32_16x16x32_bf16(v0, pf, o0, 0, 0, 0);
      o1 = __builtin_amdgcn_mfma_f32_16x16x32_bf16(v1, pf, o1, 0, 0, 0);
    }
  }
  // reduce l over lane groups (kv quarters)
  l_i += __shfl_xor(l_i, 16, 64);
  l_i += __shfl_xor(l_i, 32, 64);
  int f = (b * NHEAD_ + h) * M_ + qt * 64 + w * 16 + lq;
  float* pp = (quar == 0 ? po0 : quar == 1 ? po1 : quar == 2 ? po2 : po3) + (size_t)f * 32;
  #pragma unroll
  for (int r2 = 0; r2 < 4; ++r2) pp[lg * 4 + r2] = o0[r2];
  #pragma unroll
  for (int r2 = 0; r2 < 4; ++r2) pp[16 + lg * 4 + r2] = o1[r2];
  if (lg == 0) pl[quar * (16 * M_) + f] = l_i;
}

// combine: out = (sum po_q) / (sum l_q), scatter to [b][m][h*32+d]
__global__ __launch_bounds__(256) void attn_combine(
    const float* __restrict__ po0, const float* __restrict__ po1,
    const float* __restrict__ po2, const float* __restrict__ po3,
    const float* __restrict__ pl, float* __restrict__ o) {
  int idx = blockIdx.x * 256 + threadIdx.x;   // 0..262143
  int f = idx >> 3, dq = (idx & 7) * 4;
  float inv = 1.f / (pl[f] + pl[16 * M_ + f] + pl[32 * M_ + f] + pl[48 * M_ + f]);
  const float4 a = *(const float4*)&po0[(size_t)f * 32 + dq];
  const float4 c = *(const float4*)&po1[(size_t)f * 32 + dq];
  const float4 e = *(const float4*)&po2[(size_t)f * 32 + dq];
  const float4 g = *(const float4*)&po3[(size_t)f * 32 + dq];
  int b = f >> 14, h = (f >> 11) & 7, m = f & (M_ - 1);
  float4 r;
  r.x = (a.x + c.x + e.x + g.x) * inv;
  r.y = (a.y + c.y + e.y + g.y) * inv;
  r.z = (a.z + c.z + e.z + g.z) * inv;
  r.w = (a.w + c.w + e.w + g.w) * inv;
  *(float4*)&o[(size_t)(b * M_ + m) * D_ + h * DH_ + dq] = r;
}

// ---------------- KNN top-3 + gather/mean ----------------
__global__ __launch_bounds__(512) void knn_kernel(
    const float* __restrict__ xyz, const float* __restrict__ lt,
    float* __restrict__ out) {
  __shared__ float4 tok[2056];   // 2048 + 8 pad
  int b = blockIdx.x >> 8;                  // 256 blocks per batch
  int q0 = (blockIdx.x & 255) << 6;         // 64 queries per block
  int tid = threadIdx.x;
  for (int i = tid; i < M_; i += 512) {
    const float* tp = xyz + ((size_t)b * N_ + (size_t)i * 8) * 3;
    float a = tp[0], bb = tp[1], cc = tp[2];
    tok[i + (i >> 8)] = make_float4(a, bb, cc, a * a + bb * bb + cc * cc);
  }
  __syncthreads();
  int qi = tid >> 3, sl = tid & 7;
  int n = q0 + qi;
  const float* qp = xyz + ((size_t)b * N_ + n) * 3;
  float qx = qp[0], qy = qp[1], qz = qp[2];
  float q2 = qx * qx + qy * qy + qz * qz;
  float dd0 = INFINITY, dd1 = INFINITY, dd2 = INFINITY;
  int ii0 = 0, ii1 = 0, ii2 = 0;
  const float4* cp = &tok[sl * 257];
  int mb = sl << 8;
  #pragma unroll 4
  for (int j = 0; j < 256; ++j) {
    float4 t = cp[j];
    float dot = fmaf(qx, t.x, fmaf(qy, t.y, qz * t.z));
    float d = fmaxf(q2 + t.w - 2.f * dot, 0.f);
    if (d < dd2) {
      int m = mb + j;
      if (d < dd1) {
        dd2 = dd1; ii2 = ii1;
        if (d < dd0) { dd1 = dd0; ii1 = ii0; dd0 = d; ii0 = m; }
        else         { dd1 = d;  ii1 = m; }
      } else         { dd2 = d;  ii2 = m; }
    }
  }
  auto insT = [&](float d, int i) {
    if (d < dd2 || (d == dd2 && i < ii2)) {
      if (d < dd1 || (d == dd1 && i < ii1)) {
        dd2 = dd1; ii2 = ii1;
        if (d < dd0 || (d == dd0 && i < ii0)) { dd1 = dd0; ii1 = ii0; dd0 = d; ii0 = i; }
        else { dd1 = d; ii1 = i; }
      } else { dd2 = d; ii2 = i; }
    }
  };
  #pragma unroll
  for (int off = 1; off < 8; off <<= 1) {
    float pd0 = __shfl_xor(dd0, off, 64); int pi0 = __shfl_xor(ii0, off, 64);
    float pd1 = __shfl_xor(dd1, off, 64); int pi1 = __shfl_xor(ii1, off, 64);
    float pd2 = __shfl_xor(dd2, off, 64); int pi2 = __shfl_xor(ii2, off, 64);
    insT(pd0, pi0); insT(pd1, pi1); insT(pd2, pi2);
  }
  const float* l0 = lt + ((size_t)b * M_ + ii0) * C_;
  const float* l1 = lt + ((size_t)b * M_ + ii1) * C_;
  const float* l2 = lt + ((size_t)b * M_ + ii2) * C_;
  float* op = out + ((size_t)b * N_ + n) * C_;
  for (int cc = sl; cc < C_; cc += 8)
    op[cc] = (l0[cc] + l1[cc] + l2[cc]) * (1.f / 3.f);
}

extern "C" void kernel_launch(void* const* d_in, const int* in_sizes, int n_in,
                              void* d_out, int out_size, void* d_ws, size_t ws_size,
                              hipStream_t stream) {
  const float* xyz  = (const float*)d_in[0];
  const float* ew1  = (const float*)d_in[1];
  const float* eb1  = (const float*)d_in[2];
  const float* ew2  = (const float*)d_in[3];
  const float* eb2  = (const float*)d_in[4];
  const float* pw1  = (const float*)d_in[5];
  const float* pb1  = (const float*)d_in[6];
  const float* pw2  = (const float*)d_in[7];
  const float* pb2  = (const float*)d_in[8];
  const float* Wq   = (const float*)d_in[9];
  const float* bq   = (const float*)d_in[10];
  const float* Wk   = (const float*)d_in[11];
  const float* bk   = (const float*)d_in[12];
  const float* Wv   = (const float*)d_in[13];
  const float* bv   = (const float*)d_in[14];
  const float* Wo   = (const float*)d_in[15];
  const float* bo   = (const float*)d_in[16];
  const float* ln1s = (const float*)d_in[17];
  const float* ln1b = (const float*)d_in[18];
  const float* W1   = (const float*)d_in[19];
  const float* b1   = (const float*)d_in[20];
  const float* W2   = (const float*)d_in[21];
  const float* b2   = (const float*)d_in[22];
  const float* ln2s = (const float*)d_in[23];
  const float* ln2b = (const float*)d_in[24];
  const float* hw1  = (const float*)d_in[25];
  const float* hb1  = (const float*)d_in[26];
  const float* hw2  = (const float*)d_in[27];
  const float* hb2  = (const float*)d_in[28];
  float* out = (float*)d_out;

  float* x  = (float*)d_ws;            // 4096*256 f32
  float* y  = x  + (size_t)TOK_ * D_;  // also attn po chunk 0
  float* qb = y  + (size_t)TOK_ * D_;  // qb16 + kb16 (bf16)
  float* kb = qb + (size_t)TOK_ * D_;  // vt16 (bf16, 2MB of 4MB)
  float* vb = kb + (size_t)TOK_ * D_;  // V fp32; also attn po chunk 1
  float* ob = vb + (size_t)TOK_ * D_;
  float* ff = ob + (size_t)TOK_ * D_;  // 4096*512; also attn po chunks 2,3
  float* lt = ff + (size_t)TOK_ * FF_; // 4096*50; also attn pl

  short* qb16 = (short*)qb;
  short* kb16 = qb16 + (size_t)TOK_ * D_;
  short* vt16 = (short*)kb;
  float* po0 = y;
  float* po1 = vb;
  float* po2 = ff;
  float* po3 = ff + (size_t)TOK_ * D_;   // second half of ff
  float* pl = lt;                         // 4*32768 floats <= lt size

  embed_kernel<<<TOK_, 128, 0, stream>>>(xyz, ew1, eb1, ew2, eb2, pw1, pb1, pw2, pb2, x);

  dim3 gQKV(12, TOK_ / 32);       // (12, 128)
  dim3 gD(D_ / 64, TOK_ / 32);    // (4, 128)
  dim3 gF(FF_ / 64, TOK_ / 32);   // (8, 128)
  for (int l = 0; l < L_; ++l) {
    const float* wq = Wq + (size_t)l * D_ * D_;
    const float* wk = Wk + (size_t)l * D_ * D_;
    const float* wv = Wv + (size_t)l * D_ * D_;
    const float* wo = Wo + (size_t)l * D_ * D_;
    ln_kernel<<<TOK_ / 4, 256, 0, stream>>>(x, ln1s + l * D_, ln1b + l * D_, y);
    qkv_mfma<<<gQKV, 256, 0, stream>>>(y, wq, wk, wv, bq + l * D_, bk + l * D_, bv + l * D_, qb16, kb16, vb);
    vtrans_kernel<<<512, 256, 0, stream>>>(vb, vt16);
    attn_mfma_kernel<<<2048, 256, 0, stream>>>(qb16, kb16, vt16, po0, po1, po2, po3, pl);
    attn_combine<<<1024, 256, 0, stream>>>(po0, po1, po2, po3, pl, ob);
    gemm_mfma<0, 1><<<gD, 256, 0, stream>>>(ob, wo, bo + l * D_, x, x, D_, D_);
    ln_kernel<<<TOK_ / 4, 256, 0, stream>>>(x, ln2s + l * D_, ln2b + l * D_, y);
    gemm_mfma<2, 0><<<gF, 256, 0, stream>>>(y, W1 + (size_t)l * D_ * FF_, b1 + l * FF_, nullptr, ff, D_, FF_);
    gemm_mfma<0, 1><<<gD, 256, 0, stream>>>(ff, W2 + (size_t)l * FF_ * D_, b2 + l * D_, x, x, FF_, D_);
  }
  gemm_mfma<1, 0><<<dim3(HHID_ / 64, TOK_ / 32), 256, 0, stream>>>(x, hw1, hb1, nullptr, y, D_, HHID_);
  head2_kernel<<<TOK_ / 4, 256, 0, stream>>>(y, hw2, hb2, lt);
  knn_kernel<<<512, 512, 0, stream>>>(xyz, lt, out);
}

// Round 9
// 411.067 us; speedup vs baseline: 1.3904x; 1.0112x over previous
//
#include <hip/hip_runtime.h>
#include <hip/hip_bf16.h>
#include <math.h>

#define B_ 2
#define N_ 16384
#define M_ 2048
#define D_ 256
#define NHEAD_ 8
#define DH_ 32
#define FF_ 512
#define C_ 50
#define HID_ 128
#define HHID_ 256
#define L_ 4
#define EPS_ 1e-5f
#define TOK_ (B_*M_)   // 4096
// (1/sqrt(32)) * log2(e): folds softmax scale AND exp->exp2 into Q
#define QSCALE_ 0.25507604155757994f

typedef short short8 __attribute__((ext_vector_type(8)));
typedef short short4_t __attribute__((ext_vector_type(4)));
typedef float f32x4 __attribute__((ext_vector_type(4)));

__device__ __forceinline__ short f2bf(float f) {
  union { float f; unsigned u; } c; c.f = f;
  unsigned u = c.u;
  unsigned r = (u + 0x7FFFu + ((u >> 16) & 1u)) >> 16;
  return (short)r;
}
__device__ __forceinline__ float fast_exp2(float x) {
  float r;
  asm("v_exp_f32 %0, %1" : "=v"(r) : "v"(x));
  return r;
}
__device__ __forceinline__ unsigned cvt_pk_bf16(float lo, float hi) {
  unsigned r;
  asm("v_cvt_pk_bf16_f32 %0, %1, %2" : "=v"(r) : "v"(lo), "v"(hi));
  return r;
}

// ---------------- one-time weight convert + transpose to bf16 [N][K] ----------------
__global__ __launch_bounds__(256) void wconv_all(
    const float* __restrict__ Wq, const float* __restrict__ Wk,
    const float* __restrict__ Wv, const float* __restrict__ Wo,
    const float* __restrict__ W1, const float* __restrict__ W2,
    const float* __restrict__ h1,
    short* __restrict__ WqT, short* __restrict__ WkT,
    short* __restrict__ WvT, short* __restrict__ WoT,
    short* __restrict__ W1T, short* __restrict__ W2T, short* __restrict__ h1T) {
  int bid = blockIdx.x;
  const float* W; short* WT; int Kd, Nd, tn, tk;
  if (bid < 256) {
    int mat = bid >> 6, rem = bid & 63, l = rem >> 4, t = rem & 15;
    W  = (mat == 0 ? Wq : mat == 1 ? Wk : mat == 2 ? Wv : Wo) + l * 65536;
    WT = (mat == 0 ? WqT : mat == 1 ? WkT : mat == 2 ? WvT : WoT) + l * 65536;
    Kd = 256; Nd = 256; tn = t & 3; tk = t >> 2;
  } else if (bid < 384) {
    int rem = bid - 256, l = rem >> 5, t = rem & 31;
    W = W1 + l * 131072; WT = W1T + l * 131072;
    Kd = 256; Nd = 512; tn = t & 7; tk = t >> 3;
  } else if (bid < 512) {
    int rem = bid - 384, l = rem >> 5, t = rem & 31;
    W = W2 + l * 131072; WT = W2T + l * 131072;
    Kd = 512; Nd = 256; tn = t & 3; tk = t >> 2;
  } else {
    int t = bid - 512;
    W = h1; WT = h1T; Kd = 256; Nd = 256; tn = t & 3; tk = t >> 2;
  }
  int n0 = tn * 64, k0 = tk * 64;
  __shared__ short ts[64][72];
  int tid = threadIdx.x;
  #pragma unroll
  for (int i = 0; i < 4; ++i) {
    int r = i * 16 + (tid >> 4);
    int c4 = (tid & 15) * 4;
    float4 v = *(const float4*)&W[(size_t)(k0 + r) * Nd + n0 + c4];
    ts[c4 + 0][r] = f2bf(v.x);
    ts[c4 + 1][r] = f2bf(v.y);
    ts[c4 + 2][r] = f2bf(v.z);
    ts[c4 + 3][r] = f2bf(v.w);
  }
  __syncthreads();
  #pragma unroll
  for (int i = 0; i < 2; ++i) {
    int n = i * 32 + (tid >> 3);
    int kc = (tid & 7) * 8;
    *(short8*)&WT[(size_t)(n0 + n) * Kd + k0 + kc] = *(short8*)&ts[n][kc];
  }
}

// ---------------- fused embed + pos MLP ----------------
__global__ __launch_bounds__(128) void embed_kernel(
    const float* __restrict__ xyz,
    const float* __restrict__ ew1, const float* __restrict__ eb1,
    const float* __restrict__ ew2, const float* __restrict__ eb2,
    const float* __restrict__ pw1, const float* __restrict__ pb1,
    const float* __restrict__ pw2, const float* __restrict__ pb2,
    float* __restrict__ x) {
  int t = blockIdx.x;           // 0..4095
  int b = t / M_, m = t % M_;
  const float* p = xyz + ((size_t)b * N_ + (size_t)m * 8) * 3;
  float t0 = p[0], t1 = p[1], t2 = p[2];
  __shared__ float he[HID_], hp[HID_];
  int j = threadIdx.x;          // 128 threads
  {
    float a = fmaf(t0, ew1[j], fmaf(t1, ew1[HID_ + j], fmaf(t2, ew1[2 * HID_ + j], eb1[j])));
    he[j] = fmaxf(a, 0.f);
    float c = fmaf(t0, pw1[j], fmaf(t1, pw1[HID_ + j], fmaf(t2, pw1[2 * HID_ + j], pb1[j])));
    hp[j] = fmaxf(c, 0.f);
  }
  __syncthreads();
  for (int d = j; d < D_; d += HID_) {
    float acc = eb2[d] + pb2[d];
    for (int k = 0; k < HID_; ++k) {
      acc = fmaf(he[k], ew2[k * D_ + d], acc);
      acc = fmaf(hp[k], pw2[k * D_ + d], acc);
    }
    x[(size_t)t * D_ + d] = acc;
  }
}

// ---------------- LayerNorm -> bf16 (4 rows/block, one wave each) ----------------
__global__ __launch_bounds__(256) void ln_kernel(
    const float* __restrict__ x, const float* __restrict__ s,
    const float* __restrict__ bb, short* __restrict__ y16) {
  int r = blockIdx.x * 4 + (threadIdx.x >> 6);
  int t = threadIdx.x & 63;
  const float4* xr = (const float4*)(x + (size_t)r * D_);
  float4 v = xr[t];
  float sum = v.x + v.y + v.z + v.w;
  #pragma unroll
  for (int o = 1; o < 64; o <<= 1) sum += __shfl_xor(sum, o, 64);
  float mean = sum * (1.f / D_);
  float dx = v.x - mean, dy = v.y - mean, dz = v.z - mean, dw = v.w - mean;
  float vs = dx * dx + dy * dy + dz * dz + dw * dw;
  #pragma unroll
  for (int o = 1; o < 64; o <<= 1) vs += __shfl_xor(vs, o, 64);
  float inv = 1.0f / sqrtf(vs * (1.f / D_) + EPS_);
  float4 sv = ((const float4*)s)[t];
  float4 bv = ((const float4*)bb)[t];
  short4_t ov;
  ov[0] = f2bf(dx * inv * sv.x + bv.x);
  ov[1] = f2bf(dy * inv * sv.y + bv.y);
  ov[2] = f2bf(dz * inv * sv.z + bv.z);
  ov[3] = f2bf(dw * inv * sv.w + bv.w);
  *(short4_t*)(y16 + (size_t)r * D_ + t * 4) = ov;
}

// ---------------- head2: one wave per token, lane = output class ----------------
__global__ __launch_bounds__(256) void head2_kernel(
    const float* __restrict__ y, const float* __restrict__ w2,
    const float* __restrict__ b2, float* __restrict__ lt) {
  __shared__ float ys[4][HHID_];
  int w = threadIdx.x >> 6, l = threadIdx.x & 63;
  int t = blockIdx.x * 4 + w;
  float4 v = ((const float4*)(y + (size_t)t * HHID_))[l];
  *(float4*)&ys[w][l * 4] = v;
  int c = l < C_ ? l : 0;
  float a0 = 0.f, a1 = 0.f, a2 = 0.f, a3 = 0.f;
  #pragma unroll 4
  for (int k = 0; k < HHID_; k += 4) {
    a0 = fmaf(ys[w][k + 0], w2[(k + 0) * C_ + c], a0);
    a1 = fmaf(ys[w][k + 1], w2[(k + 1) * C_ + c], a1);
    a2 = fmaf(ys[w][k + 2], w2[(k + 2) * C_ + c], a2);
    a3 = fmaf(ys[w][k + 3], w2[(k + 3) * C_ + c], a3);
  }
  if (l < C_) lt[(size_t)t * C_ + l] = (a0 + a1) + (a2 + a3) + b2[l];
}

// ---------------- all-bf16 MFMA GEMM: A16 [M][K], WT [N][K] bf16 ----------------
// BM=32, BN=64, BK=32, 4 waves (16x32 each)
template <int ACT, int RES>
__device__ __forceinline__ void gemm16_body(
    const short* __restrict__ A16, const short* __restrict__ WT,
    const float* __restrict__ bias, const float* __restrict__ R,
    float* __restrict__ C, short* __restrict__ C16, float oscale,
    int K, int Ncols, int m0, int n0) {
  __shared__ short As[32][40];
  __shared__ short Bs[64][40];
  int tid = threadIdx.x;
  int w = tid >> 6, l = tid & 63;
  int lq = l & 15, lg = l >> 4;
  int wr = (w & 1) * 16, wc = (w >> 1) * 32;
  int ar = tid >> 3, ak = (tid & 7) * 4;
  int wn = tid & 63, wk = (tid >> 6) * 8;
  f32x4 acc0 = {0.f, 0.f, 0.f, 0.f};
  f32x4 acc1 = {0.f, 0.f, 0.f, 0.f};
  for (int kk = 0; kk < K; kk += 32) {
    __syncthreads();
    *(short4_t*)&As[ar][ak] = *(const short4_t*)&A16[(size_t)(m0 + ar) * K + kk + ak];
    *(short8*)&Bs[wn][wk]   = *(const short8*)&WT[(size_t)(n0 + wn) * K + kk + wk];
    __syncthreads();
    short8 af = *(short8*)&As[wr + lq][lg * 8];
    short8 b0 = *(short8*)&Bs[wc + lq][lg * 8];
    short8 b1 = *(short8*)&Bs[wc + 16 + lq][lg * 8];
    acc0 = __builtin_amdgcn_mfma_f32_16x16x32_bf16(af, b0, acc0, 0, 0, 0);
    acc1 = __builtin_amdgcn_mfma_f32_16x16x32_bf16(af, b1, acc1, 0, 0, 0);
  }
  int row = m0 + wr + lg * 4;
  #pragma unroll
  for (int r = 0; r < 4; ++r) {
    #pragma unroll
    for (int fj = 0; fj < 2; ++fj) {
      int col = n0 + wc + fj * 16 + lq;
      float v = (fj ? acc1[r] : acc0[r]) + bias[col];
      if (ACT == 1) v = fmaxf(v, 0.f);
      else if (ACT == 2) v = 0.5f * v * (1.f + erff(v * 0.70710678118654752f));
      if (RES) v += R[(size_t)(row + r) * Ncols + col];
      if (C)   C[(size_t)(row + r) * Ncols + col] = v;
      if (C16) C16[(size_t)(row + r) * Ncols + col] = f2bf(v * oscale);
    }
  }
}

template <int ACT, int RES>
__global__ __launch_bounds__(256) void gemm16(
    const short* __restrict__ A16, const short* __restrict__ WT,
    const float* __restrict__ bias, const float* __restrict__ R,
    float* __restrict__ C, short* __restrict__ C16,
    int K, int Ncols) {
  gemm16_body<ACT, RES>(A16, WT, bias, R, C, C16, 1.f, K, Ncols,
                        blockIdx.y * 32, blockIdx.x * 64);
}

// QKV: Q -> bf16 scaled by QSCALE_, K -> bf16, V -> bf16
__global__ __launch_bounds__(256) void qkv16(
    const short* __restrict__ A16,
    const short* __restrict__ WqT, const short* __restrict__ WkT, const short* __restrict__ WvT,
    const float* __restrict__ bq, const float* __restrict__ bk, const float* __restrict__ bv,
    short* __restrict__ q16, short* __restrict__ k16, short* __restrict__ v16) {
  int sel = blockIdx.x >> 2;
  int n0 = (blockIdx.x & 3) << 6;
  const short* WT = sel == 0 ? WqT : (sel == 1 ? WkT : WvT);
  const float* bb = sel == 0 ? bq : (sel == 1 ? bk : bv);
  short* out16 = sel == 0 ? q16 : (sel == 1 ? k16 : v16);
  float oscale = sel == 0 ? QSCALE_ : 1.f;
  gemm16_body<0, 0>(A16, WT, bb, nullptr, nullptr, out16, oscale, D_, D_,
                    blockIdx.y * 32, n0);
}

// ---------------- V transpose: v16 bf16 [tok][256] -> vt16 bf16 [b][h][32][2048] ----------------
__global__ __launch_bounds__(256) void vtrans_kernel(
    const short* __restrict__ v16, short* __restrict__ vt16) {
  int bid = blockIdx.x;
  int mt = bid & 31;
  int h = (bid >> 5) & 7;
  int b = bid >> 8;
  __shared__ short ts[64][40];
  int m0 = mt * 64;
  int tid = threadIdx.x;
  int mm = tid >> 2, dd = (tid & 3) * 8;
  *(short8*)&ts[mm][dd] =
      *(const short8*)&v16[(size_t)(b * M_ + m0 + mm) * D_ + h * DH_ + dd];
  __syncthreads();
  int d = tid >> 3, mc = (tid & 7) * 8;
  short8 r;
  #pragma unroll
  for (int j = 0; j < 8; ++j) r[j] = ts[mc + j][d];
  *(short8*)&vt16[(size_t)((b * NHEAD_ + h) * DH_ + d) * M_ + m0 + mc] = r;
}

// ---------------- flash attention: no-max exp2 softmax, KV-split x4 ----------------
#define KSTR 40
#define VSTR 72
#define PSTR 72
__global__ __launch_bounds__(256) void attn_mfma_kernel(
    const short* __restrict__ q16, const short* __restrict__ k16,
    const short* __restrict__ vt16,
    float* __restrict__ po0, float* __restrict__ po1,
    float* __restrict__ po2, float* __restrict__ po3,
    float* __restrict__ pl) {
  __shared__ short Ks[64][KSTR];
  __shared__ short Vt[32][VSTR];
  __shared__ short Ps[4][16][PSTR];
  int bid = blockIdx.x;
  int quar = bid & 3;
  int qt = (bid >> 2) & 31;
  int h  = (bid >> 7) & 7;
  int b  = bid >> 10;
  int tid = threadIdx.x;
  int w  = tid >> 6;
  int l  = tid & 63;
  int lq = l & 15;
  int lg = l >> 4;

  short8 qf = *(const short8*)&q16[(size_t)(b * M_ + qt * 64 + w * 16 + lq) * D_ + h * DH_ + lg * 8];

  float l_i = 0.f;
  f32x4 o0 = {0.f, 0.f, 0.f, 0.f};
  f32x4 o1 = {0.f, 0.f, 0.f, 0.f};
  int srow = tid >> 2, scol = (tid & 3) * 8;
  int vd = tid >> 3, vm = (tid & 7) * 8;
  const short* kp = k16 + (size_t)(b * M_ + quar * 512 + srow) * D_ + h * DH_ + scol;
  const short* vp = vt16 + (size_t)((b * NHEAD_ + h) * DH_ + vd) * M_ + quar * 512 + vm;

  for (int kt = 0; kt < 8; ++kt) {
    __syncthreads();
    *(short8*)&Ks[srow][scol] = *(const short8*)(kp + (size_t)(kt * 64) * D_);
    *(short8*)&Vt[vd][vm]     = *(const short8*)(vp + kt * 64);
    __syncthreads();
    f32x4 st[4];
    #pragma unroll
    for (int t = 0; t < 4; ++t) {
      short8 kf = *(short8*)&Ks[t * 16 + lq][lg * 8];
      f32x4 z = {0.f, 0.f, 0.f, 0.f};
      st[t] = __builtin_amdgcn_mfma_f32_16x16x32_bf16(kf, qf, z, 0, 0, 0);
    }
    #pragma unroll
    for (int t = 0; t < 4; ++t)
      #pragma unroll
      for (int r2 = 0; r2 < 4; ++r2) {
        st[t][r2] = fast_exp2(st[t][r2]);
        l_i += st[t][r2];
      }
    {
      unsigned* pw = (unsigned*)&Ps[w][lq][0];
      #pragma unroll
      for (int t = 0; t < 4; ++t) {
        uint2 pk;
        pk.x = cvt_pk_bf16(st[t][0], st[t][1]);
        pk.y = cvt_pk_bf16(st[t][2], st[t][3]);
        *(uint2*)(pw + t * 8 + lg * 2) = pk;
      }
    }
    #pragma unroll
    for (int c = 0; c < 2; ++c) {
      short8 pf = *(short8*)&Ps[w][lq][c * 32 + lg * 8];
      short8 v0 = *(short8*)&Vt[lq][c * 32 + lg * 8];
      short8 v1 = *(short8*)&Vt[16 + lq][c * 32 + lg * 8];
      o0 = __builtin_amdgcn_mfma_f32_16x16x32_bf16(v0, pf, o0, 0, 0, 0);
      o1 = __builtin_amdgcn_mfma_f32_16x16x32_bf16(v1, pf, o1, 0, 0, 0);
    }
  }
  l_i += __shfl_xor(l_i, 16, 64);
  l_i += __shfl_xor(l_i, 32, 64);
  int f = (b * NHEAD_ + h) * M_ + qt * 64 + w * 16 + lq;
  float* pp = (quar == 0 ? po0 : quar == 1 ? po1 : quar == 2 ? po2 : po3) + (size_t)f * 32;
  #pragma unroll
  for (int r2 = 0; r2 < 4; ++r2) pp[lg * 4 + r2] = o0[r2];
  #pragma unroll
  for (int r2 = 0; r2 < 4; ++r2) pp[16 + lg * 4 + r2] = o1[r2];
  if (lg == 0) pl[quar * (16 * M_) + f] = l_i;
}

// combine: ob16 = bf16((sum po_q) / (sum l_q)), scatter to [b][m][h*32+d]
__global__ __launch_bounds__(256) void attn_combine(
    const float* __restrict__ po0, const float* __restrict__ po1,
    const float* __restrict__ po2, const float* __restrict__ po3,
    const float* __restrict__ pl, short* __restrict__ ob16) {
  int idx = blockIdx.x * 256 + threadIdx.x;   // 0..262143
  int f = idx >> 3, dq = (idx & 7) * 4;
  float inv = 1.f / (pl[f] + pl[16 * M_ + f] + pl[32 * M_ + f] + pl[48 * M_ + f]);
  const float4 a = *(const float4*)&po0[(size_t)f * 32 + dq];
  const float4 c = *(const float4*)&po1[(size_t)f * 32 + dq];
  const float4 e = *(const float4*)&po2[(size_t)f * 32 + dq];
  const float4 g = *(const float4*)&po3[(size_t)f * 32 + dq];
  int b = f >> 14, h = (f >> 11) & 7, m = f & (M_ - 1);
  short4_t r;
  r[0] = f2bf((a.x + c.x + e.x + g.x) * inv);
  r[1] = f2bf((a.y + c.y + e.y + g.y) * inv);
  r[2] = f2bf((a.z + c.z + e.z + g.z) * inv);
  r[3] = f2bf((a.w + c.w + e.w + g.w) * inv);
  *(short4_t*)&ob16[(size_t)(b * M_ + m) * D_ + h * DH_ + dq] = r;
}

// ---------------- KNN top-3 + gather/mean: 2 queries/lane, flat insert ----------------
// 512 blocks (256/batch), 512 threads, 64 queries/block, 16 lanes/query, chunk=128
__global__ __launch_bounds__(512) void knn_kernel(
    const float* __restrict__ xyz, const float* __restrict__ lt,
    float* __restrict__ out) {
  __shared__ float4 tok[2064];   // 2048 + 16 pad (one per 128)
  int b = blockIdx.x >> 8;
  int q0 = (blockIdx.x & 255) << 6;
  int tid = threadIdx.x;
  for (int i = tid; i < M_; i += 512) {
    const float* tp = xyz + ((size_t)b * N_ + (size_t)i * 8) * 3;
    float a = tp[0], bb = tp[1], cc = tp[2];
    tok[i + (i >> 7)] = make_float4(a, bb, cc, a * a + bb * bb + cc * cc);
  }
  __syncthreads();
  int g = tid >> 4, sl = tid & 15;
  int na = q0 + g, nb = q0 + 32 + g;
  const float* qpa = xyz + ((size_t)b * N_ + na) * 3;
  const float* qpb = xyz + ((size_t)b * N_ + nb) * 3;
  float qxa = qpa[0], qya = qpa[1], qza = qpa[2];
  float qxb = qpb[0], qyb = qpb[1], qzb = qpb[2];
  float q2a = qxa * qxa + qya * qya + qza * qza;
  float q2b = qxb * qxb + qyb * qyb + qzb * qzb;
  float a0 = INFINITY, a1 = INFINITY, a2 = INFINITY;
  int ia0 = 0, ia1 = 0, ia2 = 0;
  float e0 = INFINITY, e1 = INFINITY, e2 = INFINITY;
  int ie0 = 0, ie1 = 0, ie2 = 0;
  const float4* cp = &tok[sl * 129];
  int mb0 = sl << 7;
  #pragma unroll 2
  for (int j = 0; j < 128; ++j) {
    float4 t = cp[j];
    float dota = fmaf(qxa, t.x, fmaf(qya, t.y, qza * t.z));
    float da = fmaxf(q2a + t.w - 2.f * dota, 0.f);
    float dotb = fmaf(qxb, t.x, fmaf(qyb, t.y, qzb * t.z));
    float db = fmaxf(q2b + t.w - 2.f * dotb, 0.f);
    if (da < a2) {
      bool c0 = da < a0, c1 = da < a1;
      int m = mb0 + j;
      a2 = c1 ? a1 : da;  ia2 = c1 ? ia1 : m;
      float n1 = c1 ? da : a1; int nj1 = c1 ? m : ia1;
      a1 = c0 ? a0 : n1;  ia1 = c0 ? ia0 : nj1;
      a0 = c0 ? da : a0;  ia0 = c0 ? m : ia0;
    }
    if (db < e2) {
      bool c0 = db < e0, c1 = db < e1;
      int m = mb0 + j;
      e2 = c1 ? e1 : db;  ie2 = c1 ? ie1 : m;
      float n1 = c1 ? db : e1; int nj1 = c1 ? m : ie1;
      e1 = c0 ? e0 : n1;  ie1 = c0 ? ie0 : nj1;
      e0 = c0 ? db : e0;  ie0 = c0 ? m : ie0;
    }
  }
  // merge across 16 lanes, lexicographic (d, i) -> exact top_k tie semantics
  auto insA = [&](float d, int i) {
    if (d < a2 || (d == a2 && i < ia2)) {
      if (d < a1 || (d == a1 && i < ia1)) {
        a2 = a1; ia2 = ia1;
        if (d < a0 || (d == a0 && i < ia0)) { a1 = a0; ia1 = ia0; a0 = d; ia0 = i; }
        else { a1 = d; ia1 = i; }
      } else { a2 = d; ia2 = i; }
    }
  };
  auto insB = [&](float d, int i) {
    if (d < e2 || (d == e2 && i < ie2)) {
      if (d < e1 || (d == e1 && i < ie1)) {
        e2 = e1; ie2 = ie1;
        if (d < e0 || (d == e0 && i < ie0)) { e1 = e0; ie1 = ie0; e0 = d; ie0 = i; }
        else { e1 = d; ie1 = i; }
      } else { e2 = d; ie2 = i; }
    }
  };
  #pragma unroll
  for (int off = 1; off < 16; off <<= 1) {
    float p0 = __shfl_xor(a0, off, 64); int pi0 = __shfl_xor(ia0, off, 64);
    float p1 = __shfl_xor(a1, off, 64); int pi1 = __shfl_xor(ia1, off, 64);
    float p2 = __shfl_xor(a2, off, 64); int pi2 = __shfl_xor(ia2, off, 64);
    insA(p0, pi0); insA(p1, pi1); insA(p2, pi2);
    float r0 = __shfl_xor(e0, off, 64); int ri0 = __shfl_xor(ie0, off, 64);
    float r1 = __shfl_xor(e1, off, 64); int ri1 = __shfl_xor(ie1, off, 64);
    float r2 = __shfl_xor(e2, off, 64); int ri2 = __shfl_xor(ie2, off, 64);
    insB(r0, ri0); insB(r1, ri1); insB(r2, ri2);
  }
  {
    const float* l0 = lt + ((size_t)b * M_ + ia0) * C_;
    const float* l1 = lt + ((size_t)b * M_ + ia1) * C_;
    const float* l2 = lt + ((size_t)b * M_ + ia2) * C_;
    float* op = out + ((size_t)b * N_ + na) * C_;
    for (int cc = sl; cc < C_; cc += 16)
      op[cc] = (l0[cc] + l1[cc] + l2[cc]) * (1.f / 3.f);
  }
  {
    const float* l0 = lt + ((size_t)b * M_ + ie0) * C_;
    const float* l1 = lt + ((size_t)b * M_ + ie1) * C_;
    const float* l2 = lt + ((size_t)b * M_ + ie2) * C_;
    float* op = out + ((size_t)b * N_ + nb) * C_;
    for (int cc = sl; cc < C_; cc += 16)
      op[cc] = (l0[cc] + l1[cc] + l2[cc]) * (1.f / 3.f);
  }
}

extern "C" void kernel_launch(void* const* d_in, const int* in_sizes, int n_in,
                              void* d_out, int out_size, void* d_ws, size_t ws_size,
                              hipStream_t stream) {
  const float* xyz  = (const float*)d_in[0];
  const float* ew1  = (const float*)d_in[1];
  const float* eb1  = (const float*)d_in[2];
  const float* ew2  = (const float*)d_in[3];
  const float* eb2  = (const float*)d_in[4];
  const float* pw1  = (const float*)d_in[5];
  const float* pb1  = (const float*)d_in[6];
  const float* pw2  = (const float*)d_in[7];
  const float* pb2  = (const float*)d_in[8];
  const float* Wq   = (const float*)d_in[9];
  const float* bq   = (const float*)d_in[10];
  const float* Wk   = (const float*)d_in[11];
  const float* bk   = (const float*)d_in[12];
  const float* Wv   = (const float*)d_in[13];
  const float* bv   = (const float*)d_in[14];
  const float* Wo   = (const float*)d_in[15];
  const float* bo   = (const float*)d_in[16];
  const float* ln1s = (const float*)d_in[17];
  const float* ln1b = (const float*)d_in[18];
  const float* W1   = (const float*)d_in[19];
  const float* b1   = (const float*)d_in[20];
  const float* W2   = (const float*)d_in[21];
  const float* b2   = (const float*)d_in[22];
  const float* ln2s = (const float*)d_in[23];
  const float* ln2b = (const float*)d_in[24];
  const float* hw1  = (const float*)d_in[25];
  const float* hb1  = (const float*)d_in[26];
  const float* hw2  = (const float*)d_in[27];
  const float* hb2  = (const float*)d_in[28];
  float* out = (float*)d_out;

  // ---- workspace layout ----
  float* x   = (float*)d_ws;           // 1M floats
  float* y   = x + 1048576;            // 1M floats (head1 out; attn po0)
  float* po2 = y + 1048576;            // 1M
  float* po3 = po2 + 1048576;          // 1M
  float* lt  = po3 + 1048576;          // 204800 floats (head2 out; attn pl)
  short* y16 = (short*)(lt + 204800);  // 1M shorts
  short* q16 = y16 + 1048576;
  short* k16 = q16 + 1048576;
  short* v16 = k16 + 1048576;
  short* vt16 = v16 + 1048576;
  short* ob16 = vt16 + 1048576;
  short* x16  = ob16 + 1048576;
  short* ff16 = x16 + 1048576;         // 2M shorts (attn po1 overlay)
  short* WqT = ff16 + 2097152;         // 262144 each
  short* WkT = WqT + 262144;
  short* WvT = WkT + 262144;
  short* WoT = WvT + 262144;
  short* W1T = WoT + 262144;           // 524288
  short* W2T = W1T + 524288;           // 524288
  short* h1T = W2T + 524288;           // 65536
  float* po0 = y;
  float* po1 = (float*)ff16;
  float* pl  = lt;

  wconv_all<<<528, 256, 0, stream>>>(Wq, Wk, Wv, Wo, W1, W2, hw1,
                                     WqT, WkT, WvT, WoT, W1T, W2T, h1T);
  embed_kernel<<<TOK_, 128, 0, stream>>>(xyz, ew1, eb1, ew2, eb2, pw1, pb1, pw2, pb2, x);

  dim3 gQKV(12, TOK_ / 32);       // (12, 128)
  dim3 gD(D_ / 64, TOK_ / 32);    // (4, 128)
  dim3 gF(FF_ / 64, TOK_ / 32);   // (8, 128)
  for (int l = 0; l < L_; ++l) {
    ln_kernel<<<TOK_ / 4, 256, 0, stream>>>(x, ln1s + l * D_, ln1b + l * D_, y16);
    qkv16<<<gQKV, 256, 0, stream>>>(y16, WqT + l * 65536, WkT + l * 65536, WvT + l * 65536,
                                    bq + l * D_, bk + l * D_, bv + l * D_, q16, k16, v16);
    vtrans_kernel<<<512, 256, 0, stream>>>(v16, vt16);
    attn_mfma_kernel<<<2048, 256, 0, stream>>>(q16, k16, vt16, po0, po1, po2, po3, pl);
    attn_combine<<<1024, 256, 0, stream>>>(po0, po1, po2, po3, pl, ob16);
    gemm16<0, 1><<<gD, 256, 0, stream>>>(ob16, WoT + l * 65536, bo + l * D_, x, x, nullptr, D_, D_);
    ln_kernel<<<TOK_ / 4, 256, 0, stream>>>(x, ln2s + l * D_, ln2b + l * D_, y16);
    gemm16<2, 0><<<gF, 256, 0, stream>>>(y16, W1T + l * 131072, b1 + l * FF_, nullptr, nullptr, ff16, D_, FF_);
    gemm16<0, 1><<<gD, 256, 0, stream>>>(ff16, W2T + l * 131072, b2 + l * D_, x, x, x16, FF_, D_);
  }
  gemm16<1, 0><<<gD, 256, 0, stream>>>(x16, h1T, hb1, nullptr, y, nullptr, D_, HHID_);
  head2_kernel<<<TOK_ / 4, 256, 0, stream>>>(y, hw2, hb2, lt);
  knn_kernel<<<512, 512, 0, stream>>>(xyz, lt, out);
}

// Round 10
// 402.507 us; speedup vs baseline: 1.4199x; 1.0213x over previous
//
#include <hip/hip_runtime.h>
#include <hip/hip_bf16.h>
#include <math.h>

#define B_ 2
#define N_ 16384
#define M_ 2048
#define D_ 256
#define NHEAD_ 8
#define DH_ 32
#define FF_ 512
#define C_ 50
#define HID_ 128
#define HHID_ 256
#define L_ 4
#define EPS_ 1e-5f
#define TOK_ (B_*M_)   // 4096
// (1/sqrt(32)) * log2(e): folds softmax scale AND exp->exp2 into Q
#define QSCALE_ 0.25507604155757994f

typedef short short8 __attribute__((ext_vector_type(8)));
typedef short short4_t __attribute__((ext_vector_type(4)));
typedef float f32x4 __attribute__((ext_vector_type(4)));

__device__ __forceinline__ short f2bf(float f) {
  union { float f; unsigned u; } c; c.f = f;
  unsigned u = c.u;
  unsigned r = (u + 0x7FFFu + ((u >> 16) & 1u)) >> 16;
  return (short)r;
}
__device__ __forceinline__ float fast_exp2(float x) {
  float r;
  asm("v_exp_f32 %0, %1" : "=v"(r) : "v"(x));
  return r;
}
__device__ __forceinline__ unsigned cvt_pk_bf16(float lo, float hi) {
  unsigned r;
  asm("v_cvt_pk_bf16_f32 %0, %1, %2" : "=v"(r) : "v"(lo), "v"(hi));
  return r;
}

// ---------------- one-time weight convert + transpose to bf16 [N][K] ----------------
__global__ __launch_bounds__(256) void wconv_all(
    const float* __restrict__ Wq, const float* __restrict__ Wk,
    const float* __restrict__ Wv, const float* __restrict__ Wo,
    const float* __restrict__ W1, const float* __restrict__ W2,
    const float* __restrict__ h1,
    short* __restrict__ WqT, short* __restrict__ WkT,
    short* __restrict__ WvT, short* __restrict__ WoT,
    short* __restrict__ W1T, short* __restrict__ W2T, short* __restrict__ h1T) {
  int bid = blockIdx.x;
  const float* W; short* WT; int Kd, Nd, tn, tk;
  if (bid < 256) {
    int mat = bid >> 6, rem = bid & 63, l = rem >> 4, t = rem & 15;
    W  = (mat == 0 ? Wq : mat == 1 ? Wk : mat == 2 ? Wv : Wo) + l * 65536;
    WT = (mat == 0 ? WqT : mat == 1 ? WkT : mat == 2 ? WvT : WoT) + l * 65536;
    Kd = 256; Nd = 256; tn = t & 3; tk = t >> 2;
  } else if (bid < 384) {
    int rem = bid - 256, l = rem >> 5, t = rem & 31;
    W = W1 + l * 131072; WT = W1T + l * 131072;
    Kd = 256; Nd = 512; tn = t & 7; tk = t >> 3;
  } else if (bid < 512) {
    int rem = bid - 384, l = rem >> 5, t = rem & 31;
    W = W2 + l * 131072; WT = W2T + l * 131072;
    Kd = 512; Nd = 256; tn = t & 3; tk = t >> 2;
  } else {
    int t = bid - 512;
    W = h1; WT = h1T; Kd = 256; Nd = 256; tn = t & 3; tk = t >> 2;
  }
  int n0 = tn * 64, k0 = tk * 64;
  __shared__ short ts[64][72];
  int tid = threadIdx.x;
  #pragma unroll
  for (int i = 0; i < 4; ++i) {
    int r = i * 16 + (tid >> 4);
    int c4 = (tid & 15) * 4;
    float4 v = *(const float4*)&W[(size_t)(k0 + r) * Nd + n0 + c4];
    ts[c4 + 0][r] = f2bf(v.x);
    ts[c4 + 1][r] = f2bf(v.y);
    ts[c4 + 2][r] = f2bf(v.z);
    ts[c4 + 3][r] = f2bf(v.w);
  }
  __syncthreads();
  #pragma unroll
  for (int i = 0; i < 2; ++i) {
    int n = i * 32 + (tid >> 3);
    int kc = (tid & 7) * 8;
    *(short8*)&WT[(size_t)(n0 + n) * Kd + k0 + kc] = *(short8*)&ts[n][kc];
  }
}

// ---------------- fused embed + pos MLP ----------------
__global__ __launch_bounds__(128) void embed_kernel(
    const float* __restrict__ xyz,
    const float* __restrict__ ew1, const float* __restrict__ eb1,
    const float* __restrict__ ew2, const float* __restrict__ eb2,
    const float* __restrict__ pw1, const float* __restrict__ pb1,
    const float* __restrict__ pw2, const float* __restrict__ pb2,
    float* __restrict__ x) {
  int t = blockIdx.x;           // 0..4095
  int b = t / M_, m = t % M_;
  const float* p = xyz + ((size_t)b * N_ + (size_t)m * 8) * 3;
  float t0 = p[0], t1 = p[1], t2 = p[2];
  __shared__ float he[HID_], hp[HID_];
  int j = threadIdx.x;          // 128 threads
  {
    float a = fmaf(t0, ew1[j], fmaf(t1, ew1[HID_ + j], fmaf(t2, ew1[2 * HID_ + j], eb1[j])));
    he[j] = fmaxf(a, 0.f);
    float c = fmaf(t0, pw1[j], fmaf(t1, pw1[HID_ + j], fmaf(t2, pw1[2 * HID_ + j], pb1[j])));
    hp[j] = fmaxf(c, 0.f);
  }
  __syncthreads();
  for (int d = j; d < D_; d += HID_) {
    float acc = eb2[d] + pb2[d];
    for (int k = 0; k < HID_; ++k) {
      acc = fmaf(he[k], ew2[k * D_ + d], acc);
      acc = fmaf(hp[k], pw2[k * D_ + d], acc);
    }
    x[(size_t)t * D_ + d] = acc;
  }
}

// ---------------- LayerNorm -> bf16 (4 rows/block, one wave each) ----------------
__global__ __launch_bounds__(256) void ln_kernel(
    const float* __restrict__ x, const float* __restrict__ s,
    const float* __restrict__ bb, short* __restrict__ y16) {
  int r = blockIdx.x * 4 + (threadIdx.x >> 6);
  int t = threadIdx.x & 63;
  const float4* xr = (const float4*)(x + (size_t)r * D_);
  float4 v = xr[t];
  float sum = v.x + v.y + v.z + v.w;
  #pragma unroll
  for (int o = 1; o < 64; o <<= 1) sum += __shfl_xor(sum, o, 64);
  float mean = sum * (1.f / D_);
  float dx = v.x - mean, dy = v.y - mean, dz = v.z - mean, dw = v.w - mean;
  float vs = dx * dx + dy * dy + dz * dz + dw * dw;
  #pragma unroll
  for (int o = 1; o < 64; o <<= 1) vs += __shfl_xor(vs, o, 64);
  float inv = 1.0f / sqrtf(vs * (1.f / D_) + EPS_);
  float4 sv = ((const float4*)s)[t];
  float4 bv = ((const float4*)bb)[t];
  short4_t ov;
  ov[0] = f2bf(dx * inv * sv.x + bv.x);
  ov[1] = f2bf(dy * inv * sv.y + bv.y);
  ov[2] = f2bf(dz * inv * sv.z + bv.z);
  ov[3] = f2bf(dw * inv * sv.w + bv.w);
  *(short4_t*)(y16 + (size_t)r * D_ + t * 4) = ov;
}

// ---------------- head2: one wave per token, lane = output class ----------------
__global__ __launch_bounds__(256) void head2_kernel(
    const float* __restrict__ y, const float* __restrict__ w2,
    const float* __restrict__ b2, float* __restrict__ lt) {
  __shared__ float ys[4][HHID_];
  int w = threadIdx.x >> 6, l = threadIdx.x & 63;
  int t = blockIdx.x * 4 + w;
  float4 v = ((const float4*)(y + (size_t)t * HHID_))[l];
  *(float4*)&ys[w][l * 4] = v;
  int c = l < C_ ? l : 0;
  float a0 = 0.f, a1 = 0.f, a2 = 0.f, a3 = 0.f;
  #pragma unroll 4
  for (int k = 0; k < HHID_; k += 4) {
    a0 = fmaf(ys[w][k + 0], w2[(k + 0) * C_ + c], a0);
    a1 = fmaf(ys[w][k + 1], w2[(k + 1) * C_ + c], a1);
    a2 = fmaf(ys[w][k + 2], w2[(k + 2) * C_ + c], a2);
    a3 = fmaf(ys[w][k + 3], w2[(k + 3) * C_ + c], a3);
  }
  if (l < C_) lt[(size_t)t * C_ + l] = (a0 + a1) + (a2 + a3) + b2[l];
}

// ---------------- all-bf16 MFMA GEMM: BM=64, BN=64, BK=32, 4 waves (32x32 each) ----------------
template <int ACT, int RES>
__device__ __forceinline__ void gemm16_body(
    const short* __restrict__ A16, const short* __restrict__ WT,
    const float* __restrict__ bias, const float* __restrict__ R,
    float* __restrict__ C, short* __restrict__ C16, float oscale,
    int K, int Ncols, int m0, int n0) {
  __shared__ short As[64][40];
  __shared__ short Bs[64][40];
  int tid = threadIdx.x;
  int w = tid >> 6, l = tid & 63;
  int lq = l & 15, lg = l >> 4;
  int wr = (w & 1) * 32, wc = (w >> 1) * 32;
  int sr = tid >> 2, sk = (tid & 3) * 8;
  f32x4 acc00 = {0.f, 0.f, 0.f, 0.f};
  f32x4 acc01 = {0.f, 0.f, 0.f, 0.f};
  f32x4 acc10 = {0.f, 0.f, 0.f, 0.f};
  f32x4 acc11 = {0.f, 0.f, 0.f, 0.f};
  for (int kk = 0; kk < K; kk += 32) {
    __syncthreads();
    *(short8*)&As[sr][sk] = *(const short8*)&A16[(size_t)(m0 + sr) * K + kk + sk];
    *(short8*)&Bs[sr][sk] = *(const short8*)&WT[(size_t)(n0 + sr) * K + kk + sk];
    __syncthreads();
    short8 a0 = *(short8*)&As[wr + lq][lg * 8];
    short8 a1 = *(short8*)&As[wr + 16 + lq][lg * 8];
    short8 b0 = *(short8*)&Bs[wc + lq][lg * 8];
    short8 b1 = *(short8*)&Bs[wc + 16 + lq][lg * 8];
    acc00 = __builtin_amdgcn_mfma_f32_16x16x32_bf16(a0, b0, acc00, 0, 0, 0);
    acc01 = __builtin_amdgcn_mfma_f32_16x16x32_bf16(a0, b1, acc01, 0, 0, 0);
    acc10 = __builtin_amdgcn_mfma_f32_16x16x32_bf16(a1, b0, acc10, 0, 0, 0);
    acc11 = __builtin_amdgcn_mfma_f32_16x16x32_bf16(a1, b1, acc11, 0, 0, 0);
  }
  #pragma unroll
  for (int fi = 0; fi < 2; ++fi) {
    int row = m0 + wr + fi * 16 + lg * 4;
    #pragma unroll
    for (int r = 0; r < 4; ++r) {
      #pragma unroll
      for (int fj = 0; fj < 2; ++fj) {
        int col = n0 + wc + fj * 16 + lq;
        float v = (fi == 0 ? (fj == 0 ? acc00[r] : acc01[r])
                           : (fj == 0 ? acc10[r] : acc11[r])) + bias[col];
        if (ACT == 1) v = fmaxf(v, 0.f);
        else if (ACT == 2) v = 0.5f * v * (1.f + erff(v * 0.70710678118654752f));
        if (RES) v += R[(size_t)(row + r) * Ncols + col];
        if (C)   C[(size_t)(row + r) * Ncols + col] = v;
        if (C16) C16[(size_t)(row + r) * Ncols + col] = f2bf(v * oscale);
      }
    }
  }
}

template <int ACT, int RES>
__global__ __launch_bounds__(256) void gemm16(
    const short* __restrict__ A16, const short* __restrict__ WT,
    const float* __restrict__ bias, const float* __restrict__ R,
    float* __restrict__ C, short* __restrict__ C16,
    int K, int Ncols) {
  gemm16_body<ACT, RES>(A16, WT, bias, R, C, C16, 1.f, K, Ncols,
                        blockIdx.y * 64, blockIdx.x * 64);
}

// QKV: Q -> bf16 scaled by QSCALE_, K -> bf16, V -> bf16
__global__ __launch_bounds__(256) void qkv16(
    const short* __restrict__ A16,
    const short* __restrict__ WqT, const short* __restrict__ WkT, const short* __restrict__ WvT,
    const float* __restrict__ bq, const float* __restrict__ bk, const float* __restrict__ bv,
    short* __restrict__ q16, short* __restrict__ k16, short* __restrict__ v16) {
  int sel = blockIdx.x >> 2;
  int n0 = (blockIdx.x & 3) << 6;
  const short* WT = sel == 0 ? WqT : (sel == 1 ? WkT : WvT);
  const float* bb = sel == 0 ? bq : (sel == 1 ? bk : bv);
  short* out16 = sel == 0 ? q16 : (sel == 1 ? k16 : v16);
  float oscale = sel == 0 ? QSCALE_ : 1.f;
  gemm16_body<0, 0>(A16, WT, bb, nullptr, nullptr, out16, oscale, D_, D_,
                    blockIdx.y * 64, n0);
}

// ---------------- V transpose: v16 bf16 [tok][256] -> vt16 bf16 [b][h][32][2048] ----------------
__global__ __launch_bounds__(256) void vtrans_kernel(
    const short* __restrict__ v16, short* __restrict__ vt16) {
  int bid = blockIdx.x;
  int mt = bid & 31;
  int h = (bid >> 5) & 7;
  int b = bid >> 8;
  __shared__ short ts[64][40];
  int m0 = mt * 64;
  int tid = threadIdx.x;
  int mm = tid >> 2, dd = (tid & 3) * 8;
  *(short8*)&ts[mm][dd] =
      *(const short8*)&v16[(size_t)(b * M_ + m0 + mm) * D_ + h * DH_ + dd];
  __syncthreads();
  int d = tid >> 3, mc = (tid & 7) * 8;
  short8 r;
  #pragma unroll
  for (int j = 0; j < 8; ++j) r[j] = ts[mc + j][d];
  *(short8*)&vt16[(size_t)((b * NHEAD_ + h) * DH_ + d) * M_ + m0 + mc] = r;
}

// ---------------- flash attention: no-max exp2 softmax, KV-split x4 ----------------
#define KSTR 40
#define VSTR 72
#define PSTR 72
__global__ __launch_bounds__(256) void attn_mfma_kernel(
    const short* __restrict__ q16, const short* __restrict__ k16,
    const short* __restrict__ vt16,
    float* __restrict__ po0, float* __restrict__ po1,
    float* __restrict__ po2, float* __restrict__ po3,
    float* __restrict__ pl) {
  __shared__ short Ks[64][KSTR];
  __shared__ short Vt[32][VSTR];
  __shared__ short Ps[4][16][PSTR];
  int bid = blockIdx.x;
  int quar = bid & 3;
  int qt = (bid >> 2) & 31;
  int h  = (bid >> 7) & 7;
  int b  = bid >> 10;
  int tid = threadIdx.x;
  int w  = tid >> 6;
  int l  = tid & 63;
  int lq = l & 15;
  int lg = l >> 4;

  short8 qf = *(const short8*)&q16[(size_t)(b * M_ + qt * 64 + w * 16 + lq) * D_ + h * DH_ + lg * 8];

  float l_i = 0.f;
  f32x4 o0 = {0.f, 0.f, 0.f, 0.f};
  f32x4 o1 = {0.f, 0.f, 0.f, 0.f};
  int srow = tid >> 2, scol = (tid & 3) * 8;
  int vd = tid >> 3, vm = (tid & 7) * 8;
  const short* kp = k16 + (size_t)(b * M_ + quar * 512 + srow) * D_ + h * DH_ + scol;
  const short* vp = vt16 + (size_t)((b * NHEAD_ + h) * DH_ + vd) * M_ + quar * 512 + vm;

  for (int kt = 0; kt < 8; ++kt) {
    __syncthreads();
    *(short8*)&Ks[srow][scol] = *(const short8*)(kp + (size_t)(kt * 64) * D_);
    *(short8*)&Vt[vd][vm]     = *(const short8*)(vp + kt * 64);
    __syncthreads();
    f32x4 st[4];
    #pragma unroll
    for (int t = 0; t < 4; ++t) {
      short8 kf = *(short8*)&Ks[t * 16 + lq][lg * 8];
      f32x4 z = {0.f, 0.f, 0.f, 0.f};
      st[t] = __builtin_amdgcn_mfma_f32_16x16x32_bf16(kf, qf, z, 0, 0, 0);
    }
    #pragma unroll
    for (int t = 0; t < 4; ++t)
      #pragma unroll
      for (int r2 = 0; r2 < 4; ++r2) {
        st[t][r2] = fast_exp2(st[t][r2]);
        l_i += st[t][r2];
      }
    {
      unsigned* pw = (unsigned*)&Ps[w][lq][0];
      #pragma unroll
      for (int t = 0; t < 4; ++t) {
        uint2 pk;
        pk.x = cvt_pk_bf16(st[t][0], st[t][1]);
        pk.y = cvt_pk_bf16(st[t][2], st[t][3]);
        *(uint2*)(pw + t * 8 + lg * 2) = pk;
      }
    }
    #pragma unroll
    for (int c = 0; c < 2; ++c) {
      short8 pf = *(short8*)&Ps[w][lq][c * 32 + lg * 8];
      short8 v0 = *(short8*)&Vt[lq][c * 32 + lg * 8];
      short8 v1 = *(short8*)&Vt[16 + lq][c * 32 + lg * 8];
      o0 = __builtin_amdgcn_mfma_f32_16x16x32_bf16(v0, pf, o0, 0, 0, 0);
      o1 = __builtin_amdgcn_mfma_f32_16x16x32_bf16(v1, pf, o1, 0, 0, 0);
    }
  }
  l_i += __shfl_xor(l_i, 16, 64);
  l_i += __shfl_xor(l_i, 32, 64);
  int f = (b * NHEAD_ + h) * M_ + qt * 64 + w * 16 + lq;
  float* pp = (quar == 0 ? po0 : quar == 1 ? po1 : quar == 2 ? po2 : po3) + (size_t)f * 32;
  #pragma unroll
  for (int r2 = 0; r2 < 4; ++r2) pp[lg * 4 + r2] = o0[r2];
  #pragma unroll
  for (int r2 = 0; r2 < 4; ++r2) pp[16 + lg * 4 + r2] = o1[r2];
  if (lg == 0) pl[quar * (16 * M_) + f] = l_i;
}

// combine: ob16 = bf16((sum po_q) / (sum l_q)), scatter to [b][m][h*32+d]
__global__ __launch_bounds__(256) void attn_combine(
    const float* __restrict__ po0, const float* __restrict__ po1,
    const float* __restrict__ po2, const float* __restrict__ po3,
    const float* __restrict__ pl, short* __restrict__ ob16) {
  int idx = blockIdx.x * 256 + threadIdx.x;   // 0..262143
  int f = idx >> 3, dq = (idx & 7) * 4;
  float inv = 1.f / (pl[f] + pl[16 * M_ + f] + pl[32 * M_ + f] + pl[48 * M_ + f]);
  const float4 a = *(const float4*)&po0[(size_t)f * 32 + dq];
  const float4 c = *(const float4*)&po1[(size_t)f * 32 + dq];
  const float4 e = *(const float4*)&po2[(size_t)f * 32 + dq];
  const float4 g = *(const float4*)&po3[(size_t)f * 32 + dq];
  int b = f >> 14, h = (f >> 11) & 7, m = f & (M_ - 1);
  short4_t r;
  r[0] = f2bf((a.x + c.x + e.x + g.x) * inv);
  r[1] = f2bf((a.y + c.y + e.y + g.y) * inv);
  r[2] = f2bf((a.z + c.z + e.z + g.z) * inv);
  r[3] = f2bf((a.w + c.w + e.w + g.w) * inv);
  *(short4_t*)&ob16[(size_t)(b * M_ + m) * D_ + h * DH_ + dq] = r;
}

// ---------------- KNN top-3 + gather/mean ----------------
// 1024 blocks (512/batch), 512 threads, 32 queries/block, 16 lanes/query, chunk=128
__global__ __launch_bounds__(512) void knn_kernel(
    const float* __restrict__ xyz, const float* __restrict__ lt,
    float* __restrict__ out) {
  __shared__ float4 tok[2064];   // 2048 + 16 pad (one per 128)
  int b = blockIdx.x >> 9;
  int q0 = (blockIdx.x & 511) << 5;    // 32 queries per block
  int tid = threadIdx.x;
  for (int i = tid; i < M_; i += 512) {
    const float* tp = xyz + ((size_t)b * N_ + (size_t)i * 8) * 3;
    float a = tp[0], bb = tp[1], cc = tp[2];
    tok[i + (i >> 7)] = make_float4(a, bb, cc, a * a + bb * bb + cc * cc);
  }
  __syncthreads();
  int g = tid >> 4, sl = tid & 15;
  int n = q0 + g;
  const float* qp = xyz + ((size_t)b * N_ + n) * 3;
  float qx = qp[0], qy = qp[1], qz = qp[2];
  float q2 = qx * qx + qy * qy + qz * qz;
  float dd0 = INFINITY, dd1 = INFINITY, dd2 = INFINITY;
  int ii0 = 0, ii1 = 0, ii2 = 0;
  const float4* cp = &tok[sl * 129];
  int mb = sl << 7;
  #pragma unroll 2
  for (int j = 0; j < 128; ++j) {
    float4 t = cp[j];
    float dot = fmaf(qx, t.x, fmaf(qy, t.y, qz * t.z));
    float d = fmaxf(q2 + t.w - 2.f * dot, 0.f);
    if (d < dd2) {
      int m = mb + j;
      if (d < dd1) {
        dd2 = dd1; ii2 = ii1;
        if (d < dd0) { dd1 = dd0; ii1 = ii0; dd0 = d; ii0 = m; }
        else         { dd1 = d;  ii1 = m; }
      } else         { dd2 = d;  ii2 = m; }
    }
  }
  // merge across 16 lanes, lexicographic (d, i) -> exact top_k tie semantics
  auto insT = [&](float d, int i) {
    if (d < dd2 || (d == dd2 && i < ii2)) {
      if (d < dd1 || (d == dd1 && i < ii1)) {
        dd2 = dd1; ii2 = ii1;
        if (d < dd0 || (d == dd0 && i < ii0)) { dd1 = dd0; ii1 = ii0; dd0 = d; ii0 = i; }
        else { dd1 = d; ii1 = i; }
      } else { dd2 = d; ii2 = i; }
    }
  };
  #pragma unroll
  for (int off = 1; off < 16; off <<= 1) {
    float p0 = __shfl_xor(dd0, off, 64); int pi0 = __shfl_xor(ii0, off, 64);
    float p1 = __shfl_xor(dd1, off, 64); int pi1 = __shfl_xor(ii1, off, 64);
    float p2 = __shfl_xor(dd2, off, 64); int pi2 = __shfl_xor(ii2, off, 64);
    insT(p0, pi0); insT(p1, pi1); insT(p2, pi2);
  }
  const float* l0 = lt + ((size_t)b * M_ + ii0) * C_;
  const float* l1 = lt + ((size_t)b * M_ + ii1) * C_;
  const float* l2 = lt + ((size_t)b * M_ + ii2) * C_;
  float* op = out + ((size_t)b * N_ + n) * C_;
  for (int cc = sl; cc < C_; cc += 16)
    op[cc] = (l0[cc] + l1[cc] + l2[cc]) * (1.f / 3.f);
}

extern "C" void kernel_launch(void* const* d_in, const int* in_sizes, int n_in,
                              void* d_out, int out_size, void* d_ws, size_t ws_size,
                              hipStream_t stream) {
  const float* xyz  = (const float*)d_in[0];
  const float* ew1  = (const float*)d_in[1];
  const float* eb1  = (const float*)d_in[2];
  const float* ew2  = (const float*)d_in[3];
  const float* eb2  = (const float*)d_in[4];
  const float* pw1  = (const float*)d_in[5];
  const float* pb1  = (const float*)d_in[6];
  const float* pw2  = (const float*)d_in[7];
  const float* pb2  = (const float*)d_in[8];
  const float* Wq   = (const float*)d_in[9];
  const float* bq   = (const float*)d_in[10];
  const float* Wk   = (const float*)d_in[11];
  const float* bk   = (const float*)d_in[12];
  const float* Wv   = (const float*)d_in[13];
  const float* bv   = (const float*)d_in[14];
  const float* Wo   = (const float*)d_in[15];
  const float* bo   = (const float*)d_in[16];
  const float* ln1s = (const float*)d_in[17];
  const float* ln1b = (const float*)d_in[18];
  const float* W1   = (const float*)d_in[19];
  const float* b1   = (const float*)d_in[20];
  const float* W2   = (const float*)d_in[21];
  const float* b2   = (const float*)d_in[22];
  const float* ln2s = (const float*)d_in[23];
  const float* ln2b = (const float*)d_in[24];
  const float* hw1  = (const float*)d_in[25];
  const float* hb1  = (const float*)d_in[26];
  const float* hw2  = (const float*)d_in[27];
  const float* hb2  = (const float*)d_in[28];
  float* out = (float*)d_out;

  // ---- workspace layout ----
  float* x   = (float*)d_ws;           // 1M floats
  float* y   = x + 1048576;            // 1M floats (head1 out; attn po0)
  float* po2 = y + 1048576;            // 1M
  float* po3 = po2 + 1048576;          // 1M
  float* lt  = po3 + 1048576;          // 204800 floats (head2 out; attn pl)
  short* y16 = (short*)(lt + 204800);  // 1M shorts
  short* q16 = y16 + 1048576;
  short* k16 = q16 + 1048576;
  short* v16 = k16 + 1048576;
  short* vt16 = v16 + 1048576;
  short* ob16 = vt16 + 1048576;
  short* x16  = ob16 + 1048576;
  short* ff16 = x16 + 1048576;         // 2M shorts (attn po1 overlay)
  short* WqT = ff16 + 2097152;         // 262144 each
  short* WkT = WqT + 262144;
  short* WvT = WkT + 262144;
  short* WoT = WvT + 262144;
  short* W1T = WoT + 262144;           // 524288
  short* W2T = W1T + 524288;           // 524288
  short* h1T = W2T + 524288;           // 65536
  float* po0 = y;
  float* po1 = (float*)ff16;
  float* pl  = lt;

  wconv_all<<<528, 256, 0, stream>>>(Wq, Wk, Wv, Wo, W1, W2, hw1,
                                     WqT, WkT, WvT, WoT, W1T, W2T, h1T);
  embed_kernel<<<TOK_, 128, 0, stream>>>(xyz, ew1, eb1, ew2, eb2, pw1, pb1, pw2, pb2, x);

  dim3 gQKV(12, TOK_ / 64);       // (12, 64)
  dim3 gD(D_ / 64, TOK_ / 64);    // (4, 64)
  dim3 gF(FF_ / 64, TOK_ / 64);   // (8, 64)
  for (int l = 0; l < L_; ++l) {
    ln_kernel<<<TOK_ / 4, 256, 0, stream>>>(x, ln1s + l * D_, ln1b + l * D_, y16);
    qkv16<<<gQKV, 256, 0, stream>>>(y16, WqT + l * 65536, WkT + l * 65536, WvT + l * 65536,
                                    bq + l * D_, bk + l * D_, bv + l * D_, q16, k16, v16);
    vtrans_kernel<<<512, 256, 0, stream>>>(v16, vt16);
    attn_mfma_kernel<<<2048, 256, 0, stream>>>(q16, k16, vt16, po0, po1, po2, po3, pl);
    attn_combine<<<1024, 256, 0, stream>>>(po0, po1, po2, po3, pl, ob16);
    gemm16<0, 1><<<gD, 256, 0, stream>>>(ob16, WoT + l * 65536, bo + l * D_, x, x, nullptr, D_, D_);
    ln_kernel<<<TOK_ / 4, 256, 0, stream>>>(x, ln2s + l * D_, ln2b + l * D_, y16);
    gemm16<2, 0><<<gF, 256, 0, stream>>>(y16, W1T + l * 131072, b1 + l * FF_, nullptr, nullptr, ff16, D_, FF_);
    gemm16<0, 1><<<gD, 256, 0, stream>>>(ff16, W2T + l * 131072, b2 + l * D_, x, x, x16, FF_, D_);
  }
  gemm16<1, 0><<<gD, 256, 0, stream>>>(x16, h1T, hb1, nullptr, y, nullptr, D_, HHID_);
  head2_kernel<<<TOK_ / 4, 256, 0, stream>>>(y, hw2, hb2, lt);
  knn_kernel<<<1024, 512, 0, stream>>>(xyz, lt, out);
}